// Round 18
// baseline (136.983 us; speedup 1.0000x reference)
//
#include <hip/hip_runtime.h>
#include <hip/hip_bf16.h>

#define B_  2
#define L_  2048
#define D_  1024
#define H_  16
#define DH_ 64
#define M_  (B_*L_)     // 4096
#define N1_ (3*D_)      // 3072

#define QSCALE (0.125f * 1.44269504088896340736f)   // 1/sqrt(64) * log2(e)

typedef __bf16 bf16x8 __attribute__((ext_vector_type(8)));
typedef float  f32x4  __attribute__((ext_vector_type(4)));
typedef unsigned short ushort_t;
typedef unsigned short ushort8_t __attribute__((ext_vector_type(8)));
typedef unsigned int   uintx2    __attribute__((ext_vector_type(2)));

#define MFMA16(a,b,c) __builtin_amdgcn_mfma_f32_16x16x32_bf16((a),(b),(c),0,0,0)

__device__ __forceinline__ float4 ld4(const float* p) { return *(const float4*)p; }

__device__ __forceinline__ ushort_t f2bf(float f) {
    union { float f; unsigned int u; } v; v.f = f;
    unsigned int r = (v.u + 0x7FFFu + ((v.u >> 16) & 1u)) >> 16;
    return (ushort_t)r;
}
__device__ __forceinline__ float bf2f(ushort_t u) {
    union { unsigned int u; float f; } v; v.u = ((unsigned int)u) << 16;
    return v.f;
}
// v_exp_f32 computes 2^x
__device__ __forceinline__ float exp2_(float x) {
    float r; asm("v_exp_f32 %0, %1" : "=v"(r) : "v"(x)); return r;
}
// hardware trig: input in REVOLUTIONS, reduce with v_fract first (ISA §3)
__device__ __forceinline__ float fract_(float x) {
    float r; asm("v_fract_f32 %0, %1" : "=v"(r) : "v"(x)); return r;
}
__device__ __forceinline__ float sin_rev(float x) {
    float r; asm("v_sin_f32 %0, %1" : "=v"(r) : "v"(x)); return r;
}
__device__ __forceinline__ float cos_rev(float x) {
    float r; asm("v_cos_f32 %0, %1" : "=v"(r) : "v"(x)); return r;
}
// packed f32 pair -> bf16 pair (lo = a, hi = b), RNE (same as f2bf)
__device__ __forceinline__ unsigned cvtpk(float a, float b) {
    unsigned r; asm("v_cvt_pk_bf16_f32 %0, %1, %2" : "=v"(r) : "v"(a), "v"(b)); return r;
}
// pull float from lane (byte_addr = src_lane*4)
__device__ __forceinline__ float bperm_f(int byte_addr, float v) {
    union { float f; int i; } u; u.f = v;
    u.i = __builtin_amdgcn_ds_bpermute(byte_addr, u.i);
    return u.f;
}
// async global->LDS, 16B per lane; LDS dest = wave-uniform base + lane*16
__device__ __forceinline__ void gload16(const ushort_t* g, ushort_t* l) {
    __builtin_amdgcn_global_load_lds(
        (const __attribute__((address_space(1))) unsigned int*)g,
        (__attribute__((address_space(3))) unsigned int*)l, 16, 0, 0);
}

// ---------------------------------------------------------------------------
// Fused prep: blocks [0,2048) x fp32->bf16; [2048,2816) Wqkv^T; [2816,3072) Wo^T
// ---------------------------------------------------------------------------
__global__ __launch_bounds__(256)
void prep(const float* __restrict__ x, const float* __restrict__ Wqkv,
          const float* __restrict__ Wo,
          ushort_t* __restrict__ xb, ushort_t* __restrict__ wqt,
          ushort_t* __restrict__ wot)
{
    __shared__ float vs[64][65];
    const int bid = blockIdx.x, t = threadIdx.x;
    if (bid < 2048) {
        int i = (bid * 256 + t) * 8;
        float4 a = ld4(x + i), b = ld4(x + i + 4);
        ushort8_t o;
        o[0] = f2bf(a.x); o[1] = f2bf(a.y); o[2] = f2bf(a.z); o[3] = f2bf(a.w);
        o[4] = f2bf(b.x); o[5] = f2bf(b.y); o[6] = f2bf(b.z); o[7] = f2bf(b.w);
        *(ushort8_t*)(xb + i) = o;
        return;
    }
    const float* in; ushort_t* out; int nt, kt, N;
    if (bid < 2048 + 768) {
        in = Wqkv; out = wqt; N = N1_;
        nt = (bid - 2048) % 48; kt = (bid - 2048) / 48;
    } else {
        in = Wo; out = wot; N = D_;
        nt = (bid - 2816) % 16; kt = (bid - 2816) / 16;
    }
    #pragma unroll
    for (int i = 0; i < 4; ++i) {
        int idx = t + 256 * i;
        int row = idx >> 4, c4 = idx & 15;
        float4 x4 = ld4(in + (size_t)(kt * 64 + row) * N + nt * 64 + c4 * 4);
        vs[row][c4*4+0] = x4.x; vs[row][c4*4+1] = x4.y;
        vs[row][c4*4+2] = x4.z; vs[row][c4*4+3] = x4.w;
    }
    __syncthreads();
    #pragma unroll
    for (int i = 0; i < 16; ++i) {
        int idx = t + 256 * i;
        int nc = idx >> 6, kc = idx & 63;
        out[(size_t)(nt * 64 + nc) * 1024 + kt * 64 + kc] = f2bf(vs[kc][nc]);
    }
}

// ---------------------------------------------------------------------------
// bf16 MFMA GEMM, m97 structure, tile BM x 128 (unchanged from R16).
// ---------------------------------------------------------------------------
template<int EPI, int BM, int NXB, int NWG>
__global__ __launch_bounds__(256)
void bgemm(const ushort_t* __restrict__ A, const ushort_t* __restrict__ Bt,
           float* __restrict__ Cf,
           ushort_t* __restrict__ Qo, ushort_t* __restrict__ Ko, ushort_t* __restrict__ Vo)
{
    constexpr int K  = 1024;
    constexpr int MI = BM / 32;             // acc rows per wave (4 or 2)
    __shared__ ushort_t As[BM * 64];
    __shared__ ushort_t Bs[128 * 64];
    const int t  = threadIdx.x;
    const int l  = t & 63, w = t >> 6;
    const int g  = l >> 4, ln = l & 15;
    const int wr = w >> 1, wc = w & 1;
    const int bid = blockIdx.x;
    const int lid = (bid & 7) * (NWG / 8) + (bid >> 3);
    const int m0 = (lid / NXB) * BM, n0 = (lid % NXB) * 128;

    const int srow = w * 8 + (l >> 3);
    const int sch  = (l & 7) ^ (l >> 3);
    const ushort_t* Ag = A  + ((size_t)(m0 + srow)) * K + sch * 8;
    const ushort_t* Bg = Bt + ((size_t)(n0 + srow)) * K + sch * 8;

    f32x4 acc[MI][4];
    #pragma unroll
    for (int mi = 0; mi < MI; ++mi)
        #pragma unroll
        for (int nj = 0; nj < 4; ++nj) acc[mi][nj] = f32x4{0.f, 0.f, 0.f, 0.f};

    for (int kt = 0; kt < K / 64; ++kt) {
        #pragma unroll
        for (int i = 0; i < BM / 32; ++i)
            gload16(Ag + (size_t)i * 32 * K + kt * 64, &As[i * 2048 + w * 512]);
        #pragma unroll
        for (int i = 0; i < 4; ++i)
            gload16(Bg + (size_t)i * 32 * K + kt * 64, &Bs[i * 2048 + w * 512]);
        __syncthreads();

        #pragma unroll
        for (int kk = 0; kk < 2; ++kk) {
            bf16x8 af[MI], bfv[4];
            #pragma unroll
            for (int mi = 0; mi < MI; ++mi) {
                int row  = (BM / 2) * wr + 16 * mi + ln;
                int phys = (4 * kk + g) ^ (ln & 7);
                af[mi] = *(const bf16x8*)&As[row * 64 + phys * 8];
            }
            #pragma unroll
            for (int nj = 0; nj < 4; ++nj) {
                int row  = 64 * wc + 16 * nj + ln;
                int phys = (4 * kk + g) ^ (ln & 7);
                bfv[nj] = *(const bf16x8*)&Bs[row * 64 + phys * 8];
            }
            #pragma unroll
            for (int mi = 0; mi < MI; ++mi)
                #pragma unroll
                for (int nj = 0; nj < 4; ++nj)
                    acc[mi][nj] = MFMA16(af[mi], bfv[nj], acc[mi][nj]);
        }
        __syncthreads();   // final iteration: all LDS reads done -> As reusable
    }

    if (EPI == 0) {
        #pragma unroll
        for (int mi = 0; mi < MI; ++mi) {
            #pragma unroll
            for (int nj = 0; nj < 4; ++nj) {
                int n = n0 + 64 * wc + 16 * nj + ln;
                #pragma unroll
                for (int r = 0; r < 4; ++r) {
                    int m = m0 + (BM / 2) * wr + 16 * mi + 4 * g + r;
                    Cf[(size_t)m * D_ + n] = acc[mi][nj][r];
                }
            }
        }
    } else {
        const int nb    = n0 + 64 * wc;
        const int which = nb >> 10;
        const int h     = (nb >> 6) & (H_ - 1);
        if (which == 2) {
            // V: transposed scatter [bh][d][L] via wave-private LDS transpose.
            ushort_t* epi = As + (size_t)w * 1152;
            const int mb = m0 + (BM / 2) * wr;          // 64-aligned
            const int bb = mb >> 11;
            const int llb = mb & (L_ - 1);
            #pragma unroll
            for (int nj = 0; nj < 4; ++nj) {
                #pragma unroll
                for (int mi = 0; mi < MI; ++mi) {
                    uintx2 wq;
                    wq[0] = cvtpk(acc[mi][nj][0], acc[mi][nj][1]);
                    wq[1] = cvtpk(acc[mi][nj][2], acc[mi][nj][3]);
                    int unit = (4 * mi + g) ^ (2 * (ln & 7));
                    *(uintx2*)&epi[ln * 72 + unit * 4] = wq;
                }
                #pragma unroll
                for (int p = 0; p < 2; ++p) {
                    int row = (l >> 3) + 8 * p;
                    int c   = l & 7;
                    ushort8_t v8 = *(const ushort8_t*)&epi[row * 72 + 8 * c];
                    int mloc = ((2 * c) ^ (2 * (row & 7))) * 4;
                    int dh   = 16 * nj + row;
                    *(ushort8_t*)&Vo[((size_t)(bb * H_ + h) * DH_ + dh) * L_
                                     + llb + mloc] = v8;
                }
            }
        } else {                    // Q or K: fused RoPE (pairs nj & nj+2)
            ushort_t* base = (which == 0) ? Qo : Ko;
            const float scale = (which == 0) ? QSCALE : 1.0f;
            const float invr0 = exp2_(-(float)ln        * 0.41524101186f) * 0.15915494310f;
            const float invr1 = exp2_(-(float)(16 + ln) * 0.41524101186f) * 0.15915494310f;
            #pragma unroll
            for (int mi = 0; mi < MI; ++mi) {
                #pragma unroll
                for (int r = 0; r < 4; ++r) {
                    int m = m0 + (BM / 2) * wr + 16 * mi + 4 * g + r;
                    int b = m >> 11, ll = m & (L_ - 1);
                    float rv0 = fract_((float)ll * invr0);
                    float rv1 = fract_((float)ll * invr1);
                    float s0 = sin_rev(rv0), c0 = cos_rev(rv0);
                    float s1 = sin_rev(rv1), c1 = cos_rev(rv1);
                    size_t rb = ((size_t)(b * H_ + h) * L_ + ll) * DH_;
                    float a1 = acc[mi][0][r], a2 = acc[mi][2][r];
                    base[rb + ln]      = f2bf((a1 * c0 - a2 * s0) * scale);
                    base[rb + ln + 32] = f2bf((a2 * c0 + a1 * s0) * scale);
                    float b1 = acc[mi][1][r], b2 = acc[mi][3][r];
                    base[rb + 16 + ln]      = f2bf((b1 * c1 - b2 * s1) * scale);
                    base[rb + 16 + ln + 32] = f2bf((b2 * c1 + b1 * s1) * scale);
                }
            }
        }
    }
}

// ---------------------------------------------------------------------------
// Flash attention v12b (split-K, R17 kernel with the occupancy clamp
// REMOVED): R17's __launch_bounds__(512,4) forced VGPR=64 < the ~110 live
// set -> O/S spilled to scratch (WRITE 8->29.7MB, the regression). Plain
// (512) bound lets the allocator keep the accumulators in registers.
// Mechanism unchanged: 8 waves = 4 q-groups x 2 key-splits; per-wave DS
// fragment reads halve vs R15 while q/wave doubles; exact flash combine
// at the end via LDS exchange in the dead K/V/P arena.
// Layouts: A: lane holds A[ln][32kk+8g+j]; B: lane holds Bt[ln][32kk+8g+j];
//          D: lane reg r -> D[4g+r][ln]   (g=lane>>4, ln=lane&15)
// ---------------------------------------------------------------------------
__global__ __launch_bounds__(512)
void attn_mfma(const ushort_t* __restrict__ qb, const ushort_t* __restrict__ kb,
               const ushort_t* __restrict__ vt, ushort_t* __restrict__ ao)
{
    __shared__ __attribute__((aligned(16))) char lds[65536];
    ushort_t* Ks = (ushort_t*)lds;              // 16KB  [128 keys][64 d] swz
    ushort_t* Vs = (ushort_t*)(lds + 16384);    // 16KB  [64 d][128 keys] swz
    // P: per-wave 4KB at 32768 + wv*4096 (32KB). Merge arena overlays lds[0..43K)
    // after the final barrier (K/V/P all dead).

    const int t    = threadIdx.x;
    const int lane = t & 63, wv = t >> 6;       // wv in 0..7
    const int g    = lane >> 4, ln = lane & 15;
    const int qg   = wv >> 1, ks = wv & 1;
    const int bid  = blockIdx.x;                // 512 blocks
    const int lid  = (bid & 7) * 64 + (bid >> 3);
    const int bh   = lid >> 4;                  // qb-fast: 16 lids/head
    const int q0   = (lid & 15) * 128 + qg * 32;

    // Q fragments: half h covers rows q0+16h+ln
    const ushort_t* qpA = qb + ((size_t)bh * L_ + q0 + ln) * DH_;
    bf16x8 qf[2][2];
    qf[0][0] = *(const bf16x8*)(qpA + 8 * g);
    qf[0][1] = *(const bf16x8*)(qpA + 32 + 8 * g);
    qf[1][0] = *(const bf16x8*)(qpA + 16 * DH_ + 8 * g);
    qf[1][1] = *(const bf16x8*)(qpA + 16 * DH_ + 32 + 8 * g);

    const ushort_t* kp = kb + (size_t)bh * L_ * DH_;
    const ushort_t* vp = vt + (size_t)bh * DH_ * L_;

    // ones B-fragment for the l-accumulating MFMA
    union { ushort8_t u; bf16x8 v; } onesu;
    #pragma unroll
    for (int j = 0; j < 8; ++j) onesu.u[j] = 0x3F80;   // bf16 1.0
    const bf16x8 onesf = onesu.v;

    // K staging: 8 waves x 2 issues x 8 rows = 128 rows (row&7 = lane>>3)
    const int krow8 = lane >> 3;
    const int ksch  = (lane & 7) ^ krow8;
    // V staging: 8 waves x 2 issues x 4 rows = 64 d-rows
    const int vrow4 = lane >> 4;

    char* Pw = lds + 32768 + wv * 4096;         // per-wave P [32 q][64 key] swz
    const int swz = (ln & 7) << 4;

    f32x4 O[2][4], lacc[2];
    #pragma unroll
    for (int h = 0; h < 2; ++h) {
        lacc[h] = f32x4{0.f, 0.f, 0.f, 0.f};
        #pragma unroll
        for (int n = 0; n < 4; ++n) O[h][n] = f32x4{0.f, 0.f, 0.f, 0.f};
    }
    float m_q[2] = {0.f, 0.f};                  // base-2 bias (defer-max)

    auto stage = [&](int tt) {
        #pragma unroll
        for (int i = 0; i < 2; ++i) {
            int row = 16 * wv + 8 * i + krow8;
            gload16(kp + ((size_t)(tt * 128 + row)) * 64 + ksch * 8,
                    &Ks[(16 * wv + 8 * i) * 64]);
        }
        #pragma unroll
        for (int i = 0; i < 2; ++i) {
            int row  = 8 * wv + 4 * i + vrow4;
            int vsch = (lane & 15) ^ ((4 * i + vrow4) & 7);
            gload16(vp + ((size_t)row) * L_ + tt * 128 + vsch * 8,
                    &Vs[(8 * wv + 4 * i) * 128]);
        }
    };

    auto process = [&](int sub) {
        // ---- swapped QK^T, acc pre-biased by -m ----
        f32x4 S[2][4];
        #pragma unroll
        for (int h = 0; h < 2; ++h)
            #pragma unroll
            for (int n = 0; n < 4; ++n)
                S[h][n] = f32x4{-m_q[h], -m_q[h], -m_q[h], -m_q[h]};
        #pragma unroll
        for (int kk = 0; kk < 2; ++kk) {
            bf16x8 kfv[4];
            #pragma unroll
            for (int n = 0; n < 4; ++n) {
                int row  = 64 * sub + 16 * n + ln;      // row&7 == ln&7
                int phys = (4 * kk + g) ^ (ln & 7);
                kfv[n] = *(const bf16x8*)&Ks[row * 64 + phys * 8];
            }
            __builtin_amdgcn_s_setprio(1);
            #pragma unroll
            for (int n = 0; n < 4; ++n) S[0][n] = MFMA16(kfv[n], qf[0][kk], S[0][n]);
            #pragma unroll
            for (int n = 0; n < 4; ++n) S[1][n] = MFMA16(kfv[n], qf[1][kk], S[1][n]);
            __builtin_amdgcn_s_setprio(0);
        }

        // ---- softmax per half (q = 16h + ln); S is already S_true - m ----
        #pragma unroll
        for (int h = 0; h < 2; ++h) {
            float pmax;                     // lane-local max (16 values)
            {
                float a0 = fmaxf(fmaxf(S[h][0][0], S[h][0][1]), fmaxf(S[h][0][2], S[h][0][3]));
                float a1 = fmaxf(fmaxf(S[h][1][0], S[h][1][1]), fmaxf(S[h][1][2], S[h][1][3]));
                float a2 = fmaxf(fmaxf(S[h][2][0], S[h][2][1]), fmaxf(S[h][2][2], S[h][2][3]));
                float a3 = fmaxf(fmaxf(S[h][3][0], S[h][3][1]), fmaxf(S[h][3][2], S[h][3][3]));
                pmax = fmaxf(fmaxf(a0, a1), fmaxf(a2, a3));
            }
            if (!__all(pmax <= 8.0f)) {     // defer-max trigger (rare)
                pmax = fmaxf(pmax, __shfl_xor(pmax, 16));
                pmax = fmaxf(pmax, __shfl_xor(pmax, 32));
                m_q[h] += pmax;
                float al = exp2_(-pmax);
                #pragma unroll
                for (int r = 0; r < 4; ++r) {
                    float alr = bperm_f((4 * g + r) * 4, al);
                    lacc[h][r] *= alr;
                    #pragma unroll
                    for (int n = 0; n < 4; ++n) O[h][n][r] *= alr;
                }
                #pragma unroll
                for (int n = 0; n < 4; ++n) S[h][n] = S[h][n] - pmax;
            }

            #pragma unroll
            for (int n = 0; n < 4; ++n) {
                float p0 = exp2_(S[h][n][0]);
                float p1 = exp2_(S[h][n][1]);
                float p2 = exp2_(S[h][n][2]);
                float p3 = exp2_(S[h][n][3]);
                uintx2 wq;
                wq[0] = cvtpk(p0, p1);
                wq[1] = cvtpk(p2, p3);
                *(uintx2*)(Pw + 2048 * h + 128 * ln + ((32 * n + 8 * g) ^ swz)) = wq;
            }
        }

        // ---- PV + l accumulation (P wave-private; same-wave DS in-order) ----
        #pragma unroll
        for (int kk = 0; kk < 2; ++kk) {
            bf16x8 vfv[4];
            #pragma unroll
            for (int n = 0; n < 4; ++n) {
                int row  = 16 * n + ln;                 // row&7 == ln&7
                int phys = 8 * sub + ((4 * kk + g) ^ (ln & 7));
                vfv[n] = *(const bf16x8*)&Vs[row * 128 + phys * 8];
            }
            bf16x8 pa0 = *(const bf16x8*)(Pw + 128 * ln + ((64 * kk + 16 * g) ^ swz));
            bf16x8 pa1 = *(const bf16x8*)(Pw + 2048 + 128 * ln + ((64 * kk + 16 * g) ^ swz));
            __builtin_amdgcn_s_setprio(1);
            #pragma unroll
            for (int n = 0; n < 4; ++n) O[0][n] = MFMA16(pa0, vfv[n], O[0][n]);
            #pragma unroll
            for (int n = 0; n < 4; ++n) O[1][n] = MFMA16(pa1, vfv[n], O[1][n]);
            lacc[0] = MFMA16(pa0, onesf, lacc[0]);
            lacc[1] = MFMA16(pa1, onesf, lacc[1]);
            __builtin_amdgcn_s_setprio(0);
        }
    };

    for (int tt = 0; tt < L_ / 128; ++tt) {
        stage(tt);
        __syncthreads();    // tile tt fully in LDS, all waves
        process(ks);        // this wave's key-half only
        __syncthreads();    // all waves done reading before next stage
    }

    // ---- split-K merge: wave (qg,1) publishes, wave (qg,0) combines ----
    // slot: 42 floats/lane, 10752B/pair, arena = lds[0..43008) (K/V/P dead)
    float* slot = (float*)(lds + qg * 10752) + lane * 42;
    if (ks == 1) {
        slot[0] = m_q[0]; slot[1] = m_q[1];
        #pragma unroll
        for (int h = 0; h < 2; ++h)
            #pragma unroll
            for (int r = 0; r < 4; ++r) slot[2 + 4 * h + r] = lacc[h][r];
        #pragma unroll
        for (int h = 0; h < 2; ++h)
            #pragma unroll
            for (int n = 0; n < 4; ++n)
                #pragma unroll
                for (int r = 0; r < 4; ++r)
                    slot[10 + 16 * h + 4 * n + r] = O[h][n][r];
    }
    __syncthreads();
    if (ks == 1) return;

    #pragma unroll
    for (int h = 0; h < 2; ++h) {
        float m2  = slot[h];                       // partner m for q=16h+ln
        float m12 = fmaxf(m_q[h], m2);
        float a1  = exp2_(m_q[h] - m12);
        float a2  = exp2_(m2 - m12);
        #pragma unroll
        for (int r = 0; r < 4; ++r) {
            float a1r = bperm_f((4 * g + r) * 4, a1);
            float a2r = bperm_f((4 * g + r) * 4, a2);
            lacc[h][r] = lacc[h][r] * a1r + slot[2 + 4 * h + r] * a2r;
            #pragma unroll
            for (int n = 0; n < 4; ++n)
                O[h][n][r] = O[h][n][r] * a1r + slot[10 + 16 * h + 4 * n + r] * a2r;
        }
    }

    // epilogue: lacc[h][r] IS l for q=16h+4g+r; normalize, write bf16 ao
    const int b = bh >> 4, hh = bh & 15;
    #pragma unroll
    for (int h = 0; h < 2; ++h) {
        #pragma unroll
        for (int r = 0; r < 4; ++r) {
            float inv = 1.0f / lacc[h][r];
            int ql = q0 + 16 * h + 4 * g + r;
            ushort_t* dst = ao + ((size_t)(b * L_ + ql)) * D_ + hh * 64;
            #pragma unroll
            for (int n = 0; n < 4; ++n)
                dst[16 * n + ln] = f2bf(O[h][n][r] * inv);
        }
    }
}

// ---------------------------------------------------------------------------
extern "C" void kernel_launch(void* const* d_in, const int* in_sizes, int n_in,
                              void* d_out, int out_size, void* d_ws, size_t ws_size,
                              hipStream_t stream)
{
    const float* x    = (const float*)d_in[0];
    const float* Wqkv = (const float*)d_in[1];
    const float* Wo   = (const float*)d_in[2];
    float* out = (float*)d_out;

    char* ws = (char*)d_ws;                               // 64 MB layout:
    ushort_t* xb  = (ushort_t*)(ws);                      // [0,8M)   x bf16; later ao
    ushort_t* wqt = (ushort_t*)(ws + ((size_t) 8 << 20)); // [8,14M)  Wqkv^T bf16
    ushort_t* wot = (ushort_t*)(ws + ((size_t)14 << 20)); // [14,16M) Wo^T bf16
    ushort_t* qR  = (ushort_t*)(ws + ((size_t)16 << 20)); // [16,24M) q rope'd (from GEMM)
    ushort_t* kR  = (ushort_t*)(ws + ((size_t)24 << 20)); // [24,32M) k rope'd (from GEMM)
    ushort_t* vt  = (ushort_t*)(ws + ((size_t)32 << 20)); // [32,40M) v^T (from GEMM)
    ushort_t* ao  = xb;                                   // alias (xb dead post-gemm)

    prep<<<3072, 256, 0, stream>>>(x, Wqkv, Wo, xb, wqt, wot);
    bgemm<1, 128, N1_/128, 768><<<768, 256, 0, stream>>>(xb, wqt, nullptr, qR, kR, vt);
    attn_mfma<<<512, 512, 0, stream>>>(qR, kR, vt, ao);
    bgemm<0, 64, D_/128, 512><<<512, 256, 0, stream>>>(ao, wot, out, nullptr, nullptr, nullptr);
}

// Round 19
// 120.893 us; speedup vs baseline: 1.1331x; 1.1331x over previous
//
#include <hip/hip_runtime.h>
#include <hip/hip_bf16.h>

#define B_  2
#define L_  2048
#define D_  1024
#define H_  16
#define DH_ 64
#define M_  (B_*L_)     // 4096
#define N1_ (3*D_)      // 3072

#define QSCALE (0.125f * 1.44269504088896340736f)   // 1/sqrt(64) * log2(e)

typedef __bf16 bf16x8 __attribute__((ext_vector_type(8)));
typedef float  f32x4  __attribute__((ext_vector_type(4)));
typedef unsigned short ushort_t;
typedef unsigned short ushort8_t __attribute__((ext_vector_type(8)));
typedef unsigned int   uintx2    __attribute__((ext_vector_type(2)));

#define MFMA16(a,b,c) __builtin_amdgcn_mfma_f32_16x16x32_bf16((a),(b),(c),0,0,0)

__device__ __forceinline__ float4 ld4(const float* p) { return *(const float4*)p; }

__device__ __forceinline__ ushort_t f2bf(float f) {
    union { float f; unsigned int u; } v; v.f = f;
    unsigned int r = (v.u + 0x7FFFu + ((v.u >> 16) & 1u)) >> 16;
    return (ushort_t)r;
}
__device__ __forceinline__ float bf2f(ushort_t u) {
    union { unsigned int u; float f; } v; v.u = ((unsigned int)u) << 16;
    return v.f;
}
// v_exp_f32 computes 2^x
__device__ __forceinline__ float exp2_(float x) {
    float r; asm("v_exp_f32 %0, %1" : "=v"(r) : "v"(x)); return r;
}
// hardware trig: input in REVOLUTIONS, reduce with v_fract first (ISA §3)
__device__ __forceinline__ float fract_(float x) {
    float r; asm("v_fract_f32 %0, %1" : "=v"(r) : "v"(x)); return r;
}
__device__ __forceinline__ float sin_rev(float x) {
    float r; asm("v_sin_f32 %0, %1" : "=v"(r) : "v"(x)); return r;
}
__device__ __forceinline__ float cos_rev(float x) {
    float r; asm("v_cos_f32 %0, %1" : "=v"(r) : "v"(x)); return r;
}
// packed f32 pair -> bf16 pair (lo = a, hi = b), RNE (same as f2bf)
__device__ __forceinline__ unsigned cvtpk(float a, float b) {
    unsigned r; asm("v_cvt_pk_bf16_f32 %0, %1, %2" : "=v"(r) : "v"(a), "v"(b)); return r;
}
// pull float from lane (byte_addr = src_lane*4)
__device__ __forceinline__ float bperm_f(int byte_addr, float v) {
    union { float f; int i; } u; u.f = v;
    u.i = __builtin_amdgcn_ds_bpermute(byte_addr, u.i);
    return u.f;
}
// async global->LDS, 16B per lane; LDS dest = wave-uniform base + lane*16
__device__ __forceinline__ void gload16(const ushort_t* g, ushort_t* l) {
    __builtin_amdgcn_global_load_lds(
        (const __attribute__((address_space(1))) unsigned int*)g,
        (__attribute__((address_space(3))) unsigned int*)l, 16, 0, 0);
}

// ---------------------------------------------------------------------------
// Fused prep: blocks [0,2048) x fp32->bf16; [2048,2816) Wqkv^T; [2816,3072) Wo^T
// ---------------------------------------------------------------------------
__global__ __launch_bounds__(256)
void prep(const float* __restrict__ x, const float* __restrict__ Wqkv,
          const float* __restrict__ Wo,
          ushort_t* __restrict__ xb, ushort_t* __restrict__ wqt,
          ushort_t* __restrict__ wot)
{
    __shared__ float vs[64][65];
    const int bid = blockIdx.x, t = threadIdx.x;
    if (bid < 2048) {
        int i = (bid * 256 + t) * 8;
        float4 a = ld4(x + i), b = ld4(x + i + 4);
        ushort8_t o;
        o[0] = f2bf(a.x); o[1] = f2bf(a.y); o[2] = f2bf(a.z); o[3] = f2bf(a.w);
        o[4] = f2bf(b.x); o[5] = f2bf(b.y); o[6] = f2bf(b.z); o[7] = f2bf(b.w);
        *(ushort8_t*)(xb + i) = o;
        return;
    }
    const float* in; ushort_t* out; int nt, kt, N;
    if (bid < 2048 + 768) {
        in = Wqkv; out = wqt; N = N1_;
        nt = (bid - 2048) % 48; kt = (bid - 2048) / 48;
    } else {
        in = Wo; out = wot; N = D_;
        nt = (bid - 2816) % 16; kt = (bid - 2816) / 16;
    }
    #pragma unroll
    for (int i = 0; i < 4; ++i) {
        int idx = t + 256 * i;
        int row = idx >> 4, c4 = idx & 15;
        float4 x4 = ld4(in + (size_t)(kt * 64 + row) * N + nt * 64 + c4 * 4);
        vs[row][c4*4+0] = x4.x; vs[row][c4*4+1] = x4.y;
        vs[row][c4*4+2] = x4.z; vs[row][c4*4+3] = x4.w;
    }
    __syncthreads();
    #pragma unroll
    for (int i = 0; i < 16; ++i) {
        int idx = t + 256 * i;
        int nc = idx >> 6, kc = idx & 63;
        out[(size_t)(nt * 64 + nc) * 1024 + kt * 64 + kc] = f2bf(vs[kc][nc]);
    }
}

// ---------------------------------------------------------------------------
// bf16 MFMA GEMM, m97 structure, tile BM x 128. 1D grid of NWG blocks with
// XCD-chunked swizzle (NWG%8==0): lid = (bid&7)*(NWG/8) + bid>>3, n fast.
// EPI 0: fp32 C. EPI 1 (BM=128): QKV scatter, fused RoPE, V transposed
// through a wave-private LDS micro-transpose (16B coalesced stores).
// ---------------------------------------------------------------------------
template<int EPI, int BM, int NXB, int NWG>
__global__ __launch_bounds__(256)
void bgemm(const ushort_t* __restrict__ A, const ushort_t* __restrict__ Bt,
           float* __restrict__ Cf,
           ushort_t* __restrict__ Qo, ushort_t* __restrict__ Ko, ushort_t* __restrict__ Vo)
{
    constexpr int K  = 1024;
    constexpr int MI = BM / 32;             // acc rows per wave (4 or 2)
    __shared__ ushort_t As[BM * 64];
    __shared__ ushort_t Bs[128 * 64];
    const int t  = threadIdx.x;
    const int l  = t & 63, w = t >> 6;
    const int g  = l >> 4, ln = l & 15;
    const int wr = w >> 1, wc = w & 1;
    const int bid = blockIdx.x;
    const int lid = (bid & 7) * (NWG / 8) + (bid >> 3);
    const int m0 = (lid / NXB) * BM, n0 = (lid % NXB) * 128;

    const int srow = w * 8 + (l >> 3);
    const int sch  = (l & 7) ^ (l >> 3);
    const ushort_t* Ag = A  + ((size_t)(m0 + srow)) * K + sch * 8;
    const ushort_t* Bg = Bt + ((size_t)(n0 + srow)) * K + sch * 8;

    f32x4 acc[MI][4];
    #pragma unroll
    for (int mi = 0; mi < MI; ++mi)
        #pragma unroll
        for (int nj = 0; nj < 4; ++nj) acc[mi][nj] = f32x4{0.f, 0.f, 0.f, 0.f};

    for (int kt = 0; kt < K / 64; ++kt) {
        #pragma unroll
        for (int i = 0; i < BM / 32; ++i)
            gload16(Ag + (size_t)i * 32 * K + kt * 64, &As[i * 2048 + w * 512]);
        #pragma unroll
        for (int i = 0; i < 4; ++i)
            gload16(Bg + (size_t)i * 32 * K + kt * 64, &Bs[i * 2048 + w * 512]);
        __syncthreads();

        #pragma unroll
        for (int kk = 0; kk < 2; ++kk) {
            bf16x8 af[MI], bfv[4];
            #pragma unroll
            for (int mi = 0; mi < MI; ++mi) {
                int row  = (BM / 2) * wr + 16 * mi + ln;
                int phys = (4 * kk + g) ^ (ln & 7);
                af[mi] = *(const bf16x8*)&As[row * 64 + phys * 8];
            }
            #pragma unroll
            for (int nj = 0; nj < 4; ++nj) {
                int row  = 64 * wc + 16 * nj + ln;
                int phys = (4 * kk + g) ^ (ln & 7);
                bfv[nj] = *(const bf16x8*)&Bs[row * 64 + phys * 8];
            }
            #pragma unroll
            for (int mi = 0; mi < MI; ++mi)
                #pragma unroll
                for (int nj = 0; nj < 4; ++nj)
                    acc[mi][nj] = MFMA16(af[mi], bfv[nj], acc[mi][nj]);
        }
        __syncthreads();   // final iteration: all LDS reads done -> As reusable
    }

    if (EPI == 0) {
        #pragma unroll
        for (int mi = 0; mi < MI; ++mi) {
            #pragma unroll
            for (int nj = 0; nj < 4; ++nj) {
                int n = n0 + 64 * wc + 16 * nj + ln;
                #pragma unroll
                for (int r = 0; r < 4; ++r) {
                    int m = m0 + (BM / 2) * wr + 16 * mi + 4 * g + r;
                    Cf[(size_t)m * D_ + n] = acc[mi][nj][r];
                }
            }
        }
    } else {
        // all four nj share one 64-column block -> same (which, head)
        const int nb    = n0 + 64 * wc;
        const int which = nb >> 10;
        const int h     = (nb >> 6) & (H_ - 1);
        if (which == 2) {
            // V: transposed scatter [bh][d][L] via wave-private LDS transpose.
            ushort_t* epi = As + (size_t)w * 1152;
            const int mb = m0 + (BM / 2) * wr;          // 64-aligned
            const int bb = mb >> 11;
            const int llb = mb & (L_ - 1);
            #pragma unroll
            for (int nj = 0; nj < 4; ++nj) {
                #pragma unroll
                for (int mi = 0; mi < MI; ++mi) {
                    uintx2 wq;
                    wq[0] = cvtpk(acc[mi][nj][0], acc[mi][nj][1]);
                    wq[1] = cvtpk(acc[mi][nj][2], acc[mi][nj][3]);
                    int unit = (4 * mi + g) ^ (2 * (ln & 7));
                    *(uintx2*)&epi[ln * 72 + unit * 4] = wq;
                }
                #pragma unroll
                for (int p = 0; p < 2; ++p) {
                    int row = (l >> 3) + 8 * p;
                    int c   = l & 7;
                    ushort8_t v8 = *(const ushort8_t*)&epi[row * 72 + 8 * c];
                    int mloc = ((2 * c) ^ (2 * (row & 7))) * 4;
                    int dh   = 16 * nj + row;
                    *(ushort8_t*)&Vo[((size_t)(bb * H_ + h) * DH_ + dh) * L_
                                     + llb + mloc] = v8;
                }
            }
        } else {                    // Q or K: fused RoPE (pairs nj & nj+2)
            ushort_t* base = (which == 0) ? Qo : Ko;
            const float scale = (which == 0) ? QSCALE : 1.0f;
            const float invr0 = exp2_(-(float)ln        * 0.41524101186f) * 0.15915494310f;
            const float invr1 = exp2_(-(float)(16 + ln) * 0.41524101186f) * 0.15915494310f;
            #pragma unroll
            for (int mi = 0; mi < MI; ++mi) {
                #pragma unroll
                for (int r = 0; r < 4; ++r) {
                    int m = m0 + (BM / 2) * wr + 16 * mi + 4 * g + r;
                    int b = m >> 11, ll = m & (L_ - 1);
                    float rv0 = fract_((float)ll * invr0);
                    float rv1 = fract_((float)ll * invr1);
                    float s0 = sin_rev(rv0), c0 = cos_rev(rv0);
                    float s1 = sin_rev(rv1), c1 = cos_rev(rv1);
                    size_t rb = ((size_t)(b * H_ + h) * L_ + ll) * DH_;
                    float a1 = acc[mi][0][r], a2 = acc[mi][2][r];
                    base[rb + ln]      = f2bf((a1 * c0 - a2 * s0) * scale);
                    base[rb + ln + 32] = f2bf((a2 * c0 + a1 * s0) * scale);
                    float b1 = acc[mi][1][r], b2 = acc[mi][3][r];
                    base[rb + 16 + ln]      = f2bf((b1 * c1 - b2 * s1) * scale);
                    base[rb + 16 + ln + 32] = f2bf((b2 * c1 + b1 * s1) * scale);
                }
            }
        }
    }
}

// ---------------------------------------------------------------------------
// Flash attention (R16 verified optimum): 512-thread blocks, 8 waves x 16 q
// = 128 q/block sharing one K/V stage per 128-key tile; 4 waves/SIMD.
// Bias-in-acc base-2 softmax with defer-max (branch-hoisted shuffles),
// ones-MFMA l accumulation, packed P via cvt_pk, single-buffer staging,
// XCD-chunked grid swizzle (qb-fast: 4 heads per XCD chunk, K/V L2-resident).
// Layouts: A: lane holds A[ln][32kk+8g+j]; B: lane holds Bt[ln][32kk+8g+j];
//          D: lane reg r -> D[4g+r][ln]   (g=lane>>4, ln=lane&15)
// ---------------------------------------------------------------------------
__global__ __launch_bounds__(512)
void attn_mfma(const ushort_t* __restrict__ qb, const ushort_t* __restrict__ kb,
               const ushort_t* __restrict__ vt, ushort_t* __restrict__ ao)
{
    __shared__ ushort_t Ks[128 * 64];       // [key][d], 128B rows, swizzled
    __shared__ ushort_t Vs[64 * 128];       // [d][key], 256B rows, swizzled
    __shared__ ushort_t Ps[8][16 * 64];     // per-wave P [16 q][64 key], swizzled

    const int t    = threadIdx.x;
    const int lane = t & 63, wv = t >> 6;   // wv in 0..7
    const int g    = lane >> 4, ln = lane & 15;
    const int bid  = blockIdx.x;            // 512 blocks
    const int lid  = (bid & 7) * 64 + (bid >> 3);
    const int bh   = lid >> 4;              // qb-fast: 16 consecutive lids/head
    const int q0   = (lid & 15) * 128 + wv * 16;

    // Q fragments: rows q0+ln
    const ushort_t* qpA = qb + ((size_t)bh * L_ + q0 + ln) * DH_;
    bf16x8 qf0 = *(const bf16x8*)(qpA + 8 * g);
    bf16x8 qf1 = *(const bf16x8*)(qpA + 32 + 8 * g);

    const ushort_t* kp = kb + (size_t)bh * L_ * DH_;
    const ushort_t* vp = vt + (size_t)bh * DH_ * L_;

    // ones B-fragment for the l-accumulating MFMA
    union { ushort8_t u; bf16x8 v; } onesu;
    #pragma unroll
    for (int j = 0; j < 8; ++j) onesu.u[j] = 0x3F80;   // bf16 1.0
    const bf16x8 onesf = onesu.v;

    // K staging: 8 waves x 2 issues x 8 rows = 128 rows (row&7 = lane>>3)
    const int krow8 = lane >> 3;
    const int ksch  = (lane & 7) ^ krow8;
    // V staging: 8 waves x 2 issues x 4 rows = 64 d-rows
    const int vrow4 = lane >> 4;

    char* Pw = (char*)&Ps[wv][0];
    const int swz = (ln & 7) << 4;

    f32x4 O[4], lacc;
    lacc = f32x4{0.f, 0.f, 0.f, 0.f};
    #pragma unroll
    for (int n = 0; n < 4; ++n) O[n] = f32x4{0.f, 0.f, 0.f, 0.f};
    float m_q = 0.f;                        // base-2 bias (defer-max)

    auto stage = [&](int tt) {
        #pragma unroll
        for (int i = 0; i < 2; ++i) {
            int row = 16 * wv + 8 * i + krow8;
            gload16(kp + ((size_t)(tt * 128 + row)) * 64 + ksch * 8,
                    &Ks[(16 * wv + 8 * i) * 64]);
        }
        #pragma unroll
        for (int i = 0; i < 2; ++i) {
            int row  = 8 * wv + 4 * i + vrow4;
            int vsch = (lane & 15) ^ ((4 * i + vrow4) & 7);
            gload16(vp + ((size_t)row) * L_ + tt * 128 + vsch * 8,
                    &Vs[(8 * wv + 4 * i) * 128]);
        }
    };

    auto process = [&](int sub) {
        // ---- swapped QK^T, acc pre-biased by -m ----
        f32x4 S[4];
        #pragma unroll
        for (int n = 0; n < 4; ++n)
            S[n] = f32x4{-m_q, -m_q, -m_q, -m_q};
        #pragma unroll
        for (int kk = 0; kk < 2; ++kk) {
            bf16x8 kfv[4];
            #pragma unroll
            for (int n = 0; n < 4; ++n) {
                int row  = 64 * sub + 16 * n + ln;      // row&7 == ln&7
                int phys = (4 * kk + g) ^ (ln & 7);
                kfv[n] = *(const bf16x8*)&Ks[row * 64 + phys * 8];
            }
            bf16x8 a = kk ? qf1 : qf0;
            __builtin_amdgcn_s_setprio(1);
            #pragma unroll
            for (int n = 0; n < 4; ++n) S[n] = MFMA16(kfv[n], a, S[n]);
            __builtin_amdgcn_s_setprio(0);
        }

        // ---- softmax (q = ln); S is already S_true - m ----
        float pmax;                         // lane-local max (16 values)
        {
            float a0 = fmaxf(fmaxf(S[0][0], S[0][1]), fmaxf(S[0][2], S[0][3]));
            float a1 = fmaxf(fmaxf(S[1][0], S[1][1]), fmaxf(S[1][2], S[1][3]));
            float a2 = fmaxf(fmaxf(S[2][0], S[2][1]), fmaxf(S[2][2], S[2][3]));
            float a3 = fmaxf(fmaxf(S[3][0], S[3][1]), fmaxf(S[3][2], S[3][3]));
            pmax = fmaxf(fmaxf(a0, a1), fmaxf(a2, a3));
        }
        // guard aggregates over ALL lanes -> lane-local max suffices here;
        // full row max (2 shuffles) only needed inside the rare branch.
        if (!__all(pmax <= 8.0f)) {
            pmax = fmaxf(pmax, __shfl_xor(pmax, 16));
            pmax = fmaxf(pmax, __shfl_xor(pmax, 32));
            m_q += pmax;
            float al = exp2_(-pmax);
            #pragma unroll
            for (int r = 0; r < 4; ++r) {
                float alr = bperm_f((4 * g + r) * 4, al);
                lacc[r] *= alr;
                #pragma unroll
                for (int n = 0; n < 4; ++n) O[n][r] *= alr;
            }
            #pragma unroll
            for (int n = 0; n < 4; ++n) S[n] = S[n] - pmax;
        }

        #pragma unroll
        for (int n = 0; n < 4; ++n) {
            float p0 = exp2_(S[n][0]);
            float p1 = exp2_(S[n][1]);
            float p2 = exp2_(S[n][2]);
            float p3 = exp2_(S[n][3]);
            uintx2 wq;
            wq[0] = cvtpk(p0, p1);
            wq[1] = cvtpk(p2, p3);
            *(uintx2*)(Pw + 128 * ln + ((32 * n + 8 * g) ^ swz)) = wq;
        }

        // ---- PV + l accumulation (P wave-private; same-wave DS in-order) ----
        #pragma unroll
        for (int kk = 0; kk < 2; ++kk) {
            bf16x8 vfv[4];
            #pragma unroll
            for (int n = 0; n < 4; ++n) {
                int row  = 16 * n + ln;                 // row&7 == ln&7
                int phys = 8 * sub + ((4 * kk + g) ^ (ln & 7));
                vfv[n] = *(const bf16x8*)&Vs[row * 128 + phys * 8];
            }
            bf16x8 pa = *(const bf16x8*)(Pw + 128 * ln + ((64 * kk + 16 * g) ^ swz));
            __builtin_amdgcn_s_setprio(1);
            #pragma unroll
            for (int n = 0; n < 4; ++n) O[n] = MFMA16(pa, vfv[n], O[n]);
            lacc = MFMA16(pa, onesf, lacc);
            __builtin_amdgcn_s_setprio(0);
        }
    };

    for (int tt = 0; tt < L_ / 128; ++tt) {
        stage(tt);
        __syncthreads();    // drains vmcnt(0): tile tt fully in LDS, all waves
        process(0);
        process(1);
        __syncthreads();    // all waves done reading before next stage
    }

    // epilogue: lacc[r] IS l for q=4g+r; normalize, write bf16 ao
    const int b = bh >> 4, hh = bh & 15;
    #pragma unroll
    for (int r = 0; r < 4; ++r) {
        float inv = 1.0f / lacc[r];
        int ql = q0 + 4 * g + r;
        ushort_t* dst = ao + ((size_t)(b * L_ + ql)) * D_ + hh * 64;
        #pragma unroll
        for (int n = 0; n < 4; ++n)
            dst[16 * n + ln] = f2bf(O[n][r] * inv);
    }
}

// ---------------------------------------------------------------------------
extern "C" void kernel_launch(void* const* d_in, const int* in_sizes, int n_in,
                              void* d_out, int out_size, void* d_ws, size_t ws_size,
                              hipStream_t stream)
{
    const float* x    = (const float*)d_in[0];
    const float* Wqkv = (const float*)d_in[1];
    const float* Wo   = (const float*)d_in[2];
    float* out = (float*)d_out;

    char* ws = (char*)d_ws;                               // 64 MB layout:
    ushort_t* xb  = (ushort_t*)(ws);                      // [0,8M)   x bf16; later ao
    ushort_t* wqt = (ushort_t*)(ws + ((size_t) 8 << 20)); // [8,14M)  Wqkv^T bf16
    ushort_t* wot = (ushort_t*)(ws + ((size_t)14 << 20)); // [14,16M) Wo^T bf16
    ushort_t* qR  = (ushort_t*)(ws + ((size_t)16 << 20)); // [16,24M) q rope'd (from GEMM)
    ushort_t* kR  = (ushort_t*)(ws + ((size_t)24 << 20)); // [24,32M) k rope'd (from GEMM)
    ushort_t* vt  = (ushort_t*)(ws + ((size_t)32 << 20)); // [32,40M) v^T (from GEMM)
    ushort_t* ao  = xb;                                   // alias (xb dead post-gemm)

    prep<<<3072, 256, 0, stream>>>(x, Wqkv, Wo, xb, wqt, wot);
    bgemm<1, 128, N1_/128, 768><<<768, 256, 0, stream>>>(xb, wqt, nullptr, qR, kR, vt);
    attn_mfma<<<512, 512, 0, stream>>>(qR, kR, vt, ao);
    bgemm<0, 64, D_/128, 512><<<512, 256, 0, stream>>>(ao, wot, out, nullptr, nullptr, nullptr);
}

// Round 20
// 114.166 us; speedup vs baseline: 1.1999x; 1.0589x over previous
//
#include <hip/hip_runtime.h>
#include <hip/hip_bf16.h>

#define B_  2
#define L_  2048
#define D_  1024
#define H_  16
#define DH_ 64
#define M_  (B_*L_)     // 4096
#define N1_ (3*D_)      // 3072

#define QSCALE (0.125f * 1.44269504088896340736f)   // 1/sqrt(64) * log2(e)

typedef __bf16 bf16x8 __attribute__((ext_vector_type(8)));
typedef float  f32x4  __attribute__((ext_vector_type(4)));
typedef unsigned short ushort_t;
typedef unsigned short ushort8_t __attribute__((ext_vector_type(8)));
typedef unsigned int   uintx2    __attribute__((ext_vector_type(2)));

#define MFMA16(a,b,c) __builtin_amdgcn_mfma_f32_16x16x32_bf16((a),(b),(c),0,0,0)

__device__ __forceinline__ float4 ld4(const float* p) { return *(const float4*)p; }

__device__ __forceinline__ ushort_t f2bf(float f) {
    union { float f; unsigned int u; } v; v.f = f;
    unsigned int r = (v.u + 0x7FFFu + ((v.u >> 16) & 1u)) >> 16;
    return (ushort_t)r;
}
__device__ __forceinline__ float bf2f(ushort_t u) {
    union { unsigned int u; float f; } v; v.u = ((unsigned int)u) << 16;
    return v.f;
}
// v_exp_f32 computes 2^x
__device__ __forceinline__ float exp2_(float x) {
    float r; asm("v_exp_f32 %0, %1" : "=v"(r) : "v"(x)); return r;
}
// hardware trig: input in REVOLUTIONS, reduce with v_fract first (ISA §3)
__device__ __forceinline__ float fract_(float x) {
    float r; asm("v_fract_f32 %0, %1" : "=v"(r) : "v"(x)); return r;
}
__device__ __forceinline__ float sin_rev(float x) {
    float r; asm("v_sin_f32 %0, %1" : "=v"(r) : "v"(x)); return r;
}
__device__ __forceinline__ float cos_rev(float x) {
    float r; asm("v_cos_f32 %0, %1" : "=v"(r) : "v"(x)); return r;
}
// packed f32 pair -> bf16 pair (lo = a, hi = b), RNE (same as f2bf)
__device__ __forceinline__ unsigned cvtpk(float a, float b) {
    unsigned r; asm("v_cvt_pk_bf16_f32 %0, %1, %2" : "=v"(r) : "v"(a), "v"(b)); return r;
}
// pull float from lane (byte_addr = src_lane*4)
__device__ __forceinline__ float bperm_f(int byte_addr, float v) {
    union { float f; int i; } u; u.f = v;
    u.i = __builtin_amdgcn_ds_bpermute(byte_addr, u.i);
    return u.f;
}
// async global->LDS, 16B per lane; LDS dest = wave-uniform base + lane*16
__device__ __forceinline__ void gload16(const ushort_t* g, ushort_t* l) {
    __builtin_amdgcn_global_load_lds(
        (const __attribute__((address_space(1))) unsigned int*)g,
        (__attribute__((address_space(3))) unsigned int*)l, 16, 0, 0);
}

// ---------------------------------------------------------------------------
// Fused prep: blocks [0,2048) x fp32->bf16; [2048,2816) Wqkv^T; [2816,3072) Wo^T
// ---------------------------------------------------------------------------
__global__ __launch_bounds__(256)
void prep(const float* __restrict__ x, const float* __restrict__ Wqkv,
          const float* __restrict__ Wo,
          ushort_t* __restrict__ xb, ushort_t* __restrict__ wqt,
          ushort_t* __restrict__ wot)
{
    __shared__ float vs[64][65];
    const int bid = blockIdx.x, t = threadIdx.x;
    if (bid < 2048) {
        int i = (bid * 256 + t) * 8;
        float4 a = ld4(x + i), b = ld4(x + i + 4);
        ushort8_t o;
        o[0] = f2bf(a.x); o[1] = f2bf(a.y); o[2] = f2bf(a.z); o[3] = f2bf(a.w);
        o[4] = f2bf(b.x); o[5] = f2bf(b.y); o[6] = f2bf(b.z); o[7] = f2bf(b.w);
        *(ushort8_t*)(xb + i) = o;
        return;
    }
    const float* in; ushort_t* out; int nt, kt, N;
    if (bid < 2048 + 768) {
        in = Wqkv; out = wqt; N = N1_;
        nt = (bid - 2048) % 48; kt = (bid - 2048) / 48;
    } else {
        in = Wo; out = wot; N = D_;
        nt = (bid - 2816) % 16; kt = (bid - 2816) / 16;
    }
    #pragma unroll
    for (int i = 0; i < 4; ++i) {
        int idx = t + 256 * i;
        int row = idx >> 4, c4 = idx & 15;
        float4 x4 = ld4(in + (size_t)(kt * 64 + row) * N + nt * 64 + c4 * 4);
        vs[row][c4*4+0] = x4.x; vs[row][c4*4+1] = x4.y;
        vs[row][c4*4+2] = x4.z; vs[row][c4*4+3] = x4.w;
    }
    __syncthreads();
    #pragma unroll
    for (int i = 0; i < 16; ++i) {
        int idx = t + 256 * i;
        int nc = idx >> 6, kc = idx & 63;
        out[(size_t)(nt * 64 + nc) * 1024 + kt * 64 + kc] = f2bf(vs[kc][nc]);
    }
}

// ---------------------------------------------------------------------------
// bf16 MFMA GEMM, m97 structure, tile BM x 128. 1D grid of NWG blocks with
// XCD-chunked swizzle (NWG%8==0): lid = (bid&7)*(NWG/8) + bid>>3, n fast.
// EPI 0: fp32 C. EPI 1: QKV scatter, fused RoPE, V transposed through a
// wave-private padded-row LDS micro-transpose (16B coalesced stores),
// MI-generic (BM=64 or 128).
// ---------------------------------------------------------------------------
template<int EPI, int BM, int NXB, int NWG>
__global__ __launch_bounds__(256)
void bgemm(const ushort_t* __restrict__ A, const ushort_t* __restrict__ Bt,
           float* __restrict__ Cf,
           ushort_t* __restrict__ Qo, ushort_t* __restrict__ Ko, ushort_t* __restrict__ Vo)
{
    constexpr int K  = 1024;
    constexpr int MI = BM / 32;             // acc rows per wave (4 or 2)
    __shared__ ushort_t As[BM * 64];
    __shared__ ushort_t Bs[128 * 64];
    const int t  = threadIdx.x;
    const int l  = t & 63, w = t >> 6;
    const int g  = l >> 4, ln = l & 15;
    const int wr = w >> 1, wc = w & 1;
    const int bid = blockIdx.x;
    const int lid = (bid & 7) * (NWG / 8) + (bid >> 3);
    const int m0 = (lid / NXB) * BM, n0 = (lid % NXB) * 128;

    const int srow = w * 8 + (l >> 3);
    const int sch  = (l & 7) ^ (l >> 3);
    const ushort_t* Ag = A  + ((size_t)(m0 + srow)) * K + sch * 8;
    const ushort_t* Bg = Bt + ((size_t)(n0 + srow)) * K + sch * 8;

    f32x4 acc[MI][4];
    #pragma unroll
    for (int mi = 0; mi < MI; ++mi)
        #pragma unroll
        for (int nj = 0; nj < 4; ++nj) acc[mi][nj] = f32x4{0.f, 0.f, 0.f, 0.f};

    for (int kt = 0; kt < K / 64; ++kt) {
        #pragma unroll
        for (int i = 0; i < BM / 32; ++i)
            gload16(Ag + (size_t)i * 32 * K + kt * 64, &As[i * 2048 + w * 512]);
        #pragma unroll
        for (int i = 0; i < 4; ++i)
            gload16(Bg + (size_t)i * 32 * K + kt * 64, &Bs[i * 2048 + w * 512]);
        __syncthreads();

        #pragma unroll
        for (int kk = 0; kk < 2; ++kk) {
            bf16x8 af[MI], bfv[4];
            #pragma unroll
            for (int mi = 0; mi < MI; ++mi) {
                int row  = (BM / 2) * wr + 16 * mi + ln;
                int phys = (4 * kk + g) ^ (ln & 7);
                af[mi] = *(const bf16x8*)&As[row * 64 + phys * 8];
            }
            #pragma unroll
            for (int nj = 0; nj < 4; ++nj) {
                int row  = 64 * wc + 16 * nj + ln;
                int phys = (4 * kk + g) ^ (ln & 7);
                bfv[nj] = *(const bf16x8*)&Bs[row * 64 + phys * 8];
            }
            #pragma unroll
            for (int mi = 0; mi < MI; ++mi)
                #pragma unroll
                for (int nj = 0; nj < 4; ++nj)
                    acc[mi][nj] = MFMA16(af[mi], bfv[nj], acc[mi][nj]);
        }
        __syncthreads();   // final iteration: all LDS reads done -> As reusable
    }

    if (EPI == 0) {
        #pragma unroll
        for (int mi = 0; mi < MI; ++mi) {
            #pragma unroll
            for (int nj = 0; nj < 4; ++nj) {
                int n = n0 + 64 * wc + 16 * nj + ln;
                #pragma unroll
                for (int r = 0; r < 4; ++r) {
                    int m = m0 + (BM / 2) * wr + 16 * mi + 4 * g + r;
                    Cf[(size_t)m * D_ + n] = acc[mi][nj][r];
                }
            }
        }
    } else {
        // all four nj share one 64-column block -> same (which, head)
        const int nb    = n0 + 64 * wc;
        const int which = nb >> 10;
        const int h     = (nb >> 6) & (H_ - 1);
        if (which == 2) {
            // V: transposed scatter [bh][d][L] via wave-private LDS transpose.
            // Padded rows (stride 16*MI+4 ushorts) spread banks; no XOR.
            constexpr int RW = 16 * MI + 4;
            ushort_t* epi = As + (size_t)w * (16 * RW);
            const int mb = m0 + (BM / 2) * wr;     // wave's m base (MI*16 rows)
            const int bb = mb >> 11;
            const int llb = mb & (L_ - 1);
            #pragma unroll
            for (int nj = 0; nj < 4; ++nj) {
                #pragma unroll
                for (int mi = 0; mi < MI; ++mi) {
                    uintx2 wq;
                    wq[0] = cvtpk(acc[mi][nj][0], acc[mi][nj][1]);
                    wq[1] = cvtpk(acc[mi][nj][2], acc[mi][nj][3]);
                    *(uintx2*)&epi[ln * RW + (4 * mi + g) * 4] = wq;
                }
                // same-wave DS in-order: read back transposed, 16B chunks
                if (MI == 4) {
                    #pragma unroll
                    for (int p = 0; p < 2; ++p) {
                        int rr = (l >> 3) + 8 * p;     // 0..15 (n_local)
                        int c  = l & 7;                // 8 m-values at 8c
                        ushort8_t v8 = *(const ushort8_t*)&epi[rr * RW + 8 * c];
                        *(ushort8_t*)&Vo[((size_t)(bb * H_ + h) * DH_ + 16 * nj + rr) * L_
                                         + llb + 8 * c] = v8;
                    }
                } else {
                    int rr = l >> 2;                   // 0..15
                    int c  = l & 3;                    // 8 m-values at 8c
                    ushort8_t v8 = *(const ushort8_t*)&epi[rr * RW + 8 * c];
                    *(ushort8_t*)&Vo[((size_t)(bb * H_ + h) * DH_ + 16 * nj + rr) * L_
                                     + llb + 8 * c] = v8;
                }
            }
        } else {                    // Q or K: fused RoPE (pairs nj & nj+2)
            ushort_t* base = (which == 0) ? Qo : Ko;
            const float scale = (which == 0) ? QSCALE : 1.0f;
            const float invr0 = exp2_(-(float)ln        * 0.41524101186f) * 0.15915494310f;
            const float invr1 = exp2_(-(float)(16 + ln) * 0.41524101186f) * 0.15915494310f;
            #pragma unroll
            for (int mi = 0; mi < MI; ++mi) {
                #pragma unroll
                for (int r = 0; r < 4; ++r) {
                    int m = m0 + (BM / 2) * wr + 16 * mi + 4 * g + r;
                    int b = m >> 11, ll = m & (L_ - 1);
                    float rv0 = fract_((float)ll * invr0);
                    float rv1 = fract_((float)ll * invr1);
                    float s0 = sin_rev(rv0), c0 = cos_rev(rv0);
                    float s1 = sin_rev(rv1), c1 = cos_rev(rv1);
                    size_t rb = ((size_t)(b * H_ + h) * L_ + ll) * DH_;
                    float a1 = acc[mi][0][r], a2 = acc[mi][2][r];
                    base[rb + ln]      = f2bf((a1 * c0 - a2 * s0) * scale);
                    base[rb + ln + 32] = f2bf((a2 * c0 + a1 * s0) * scale);
                    float b1 = acc[mi][1][r], b2 = acc[mi][3][r];
                    base[rb + 16 + ln]      = f2bf((b1 * c1 - b2 * s1) * scale);
                    base[rb + 16 + ln + 32] = f2bf((b2 * c1 + b1 * s1) * scale);
                }
            }
        }
    }
}

// ---------------------------------------------------------------------------
// Flash attention (R16 verified optimum, unchanged): 512-thread blocks,
// 8 waves x 16 q = 128 q/block sharing one K/V stage; 4 waves/SIMD.
// ---------------------------------------------------------------------------
__global__ __launch_bounds__(512)
void attn_mfma(const ushort_t* __restrict__ qb, const ushort_t* __restrict__ kb,
               const ushort_t* __restrict__ vt, ushort_t* __restrict__ ao)
{
    __shared__ ushort_t Ks[128 * 64];       // [key][d], 128B rows, swizzled
    __shared__ ushort_t Vs[64 * 128];       // [d][key], 256B rows, swizzled
    __shared__ ushort_t Ps[8][16 * 64];     // per-wave P [16 q][64 key], swizzled

    const int t    = threadIdx.x;
    const int lane = t & 63, wv = t >> 6;   // wv in 0..7
    const int g    = lane >> 4, ln = lane & 15;
    const int bid  = blockIdx.x;            // 512 blocks
    const int lid  = (bid & 7) * 64 + (bid >> 3);
    const int bh   = lid >> 4;              // qb-fast: 16 consecutive lids/head
    const int q0   = (lid & 15) * 128 + wv * 16;

    // Q fragments: rows q0+ln
    const ushort_t* qpA = qb + ((size_t)bh * L_ + q0 + ln) * DH_;
    bf16x8 qf0 = *(const bf16x8*)(qpA + 8 * g);
    bf16x8 qf1 = *(const bf16x8*)(qpA + 32 + 8 * g);

    const ushort_t* kp = kb + (size_t)bh * L_ * DH_;
    const ushort_t* vp = vt + (size_t)bh * DH_ * L_;

    // ones B-fragment for the l-accumulating MFMA
    union { ushort8_t u; bf16x8 v; } onesu;
    #pragma unroll
    for (int j = 0; j < 8; ++j) onesu.u[j] = 0x3F80;   // bf16 1.0
    const bf16x8 onesf = onesu.v;

    // K staging: 8 waves x 2 issues x 8 rows = 128 rows (row&7 = lane>>3)
    const int krow8 = lane >> 3;
    const int ksch  = (lane & 7) ^ krow8;
    // V staging: 8 waves x 2 issues x 4 rows = 64 d-rows
    const int vrow4 = lane >> 4;

    char* Pw = (char*)&Ps[wv][0];
    const int swz = (ln & 7) << 4;

    f32x4 O[4], lacc;
    lacc = f32x4{0.f, 0.f, 0.f, 0.f};
    #pragma unroll
    for (int n = 0; n < 4; ++n) O[n] = f32x4{0.f, 0.f, 0.f, 0.f};
    float m_q = 0.f;                        // base-2 bias (defer-max)

    auto stage = [&](int tt) {
        #pragma unroll
        for (int i = 0; i < 2; ++i) {
            int row = 16 * wv + 8 * i + krow8;
            gload16(kp + ((size_t)(tt * 128 + row)) * 64 + ksch * 8,
                    &Ks[(16 * wv + 8 * i) * 64]);
        }
        #pragma unroll
        for (int i = 0; i < 2; ++i) {
            int row  = 8 * wv + 4 * i + vrow4;
            int vsch = (lane & 15) ^ ((4 * i + vrow4) & 7);
            gload16(vp + ((size_t)row) * L_ + tt * 128 + vsch * 8,
                    &Vs[(8 * wv + 4 * i) * 128]);
        }
    };

    auto process = [&](int sub) {
        // ---- swapped QK^T, acc pre-biased by -m ----
        f32x4 S[4];
        #pragma unroll
        for (int n = 0; n < 4; ++n)
            S[n] = f32x4{-m_q, -m_q, -m_q, -m_q};
        #pragma unroll
        for (int kk = 0; kk < 2; ++kk) {
            bf16x8 kfv[4];
            #pragma unroll
            for (int n = 0; n < 4; ++n) {
                int row  = 64 * sub + 16 * n + ln;      // row&7 == ln&7
                int phys = (4 * kk + g) ^ (ln & 7);
                kfv[n] = *(const bf16x8*)&Ks[row * 64 + phys * 8];
            }
            bf16x8 a = kk ? qf1 : qf0;
            __builtin_amdgcn_s_setprio(1);
            #pragma unroll
            for (int n = 0; n < 4; ++n) S[n] = MFMA16(kfv[n], a, S[n]);
            __builtin_amdgcn_s_setprio(0);
        }

        // ---- softmax (q = ln); S is already S_true - m ----
        float pmax;                         // lane-local max (16 values)
        {
            float a0 = fmaxf(fmaxf(S[0][0], S[0][1]), fmaxf(S[0][2], S[0][3]));
            float a1 = fmaxf(fmaxf(S[1][0], S[1][1]), fmaxf(S[1][2], S[1][3]));
            float a2 = fmaxf(fmaxf(S[2][0], S[2][1]), fmaxf(S[2][2], S[2][3]));
            float a3 = fmaxf(fmaxf(S[3][0], S[3][1]), fmaxf(S[3][2], S[3][3]));
            pmax = fmaxf(fmaxf(a0, a1), fmaxf(a2, a3));
        }
        // guard aggregates over ALL lanes -> lane-local max suffices here;
        // full row max (2 shuffles) only needed inside the rare branch.
        if (!__all(pmax <= 8.0f)) {
            pmax = fmaxf(pmax, __shfl_xor(pmax, 16));
            pmax = fmaxf(pmax, __shfl_xor(pmax, 32));
            m_q += pmax;
            float al = exp2_(-pmax);
            #pragma unroll
            for (int r = 0; r < 4; ++r) {
                float alr = bperm_f((4 * g + r) * 4, al);
                lacc[r] *= alr;
                #pragma unroll
                for (int n = 0; n < 4; ++n) O[n][r] *= alr;
            }
            #pragma unroll
            for (int n = 0; n < 4; ++n) S[n] = S[n] - pmax;
        }

        #pragma unroll
        for (int n = 0; n < 4; ++n) {
            float p0 = exp2_(S[n][0]);
            float p1 = exp2_(S[n][1]);
            float p2 = exp2_(S[n][2]);
            float p3 = exp2_(S[n][3]);
            uintx2 wq;
            wq[0] = cvtpk(p0, p1);
            wq[1] = cvtpk(p2, p3);
            *(uintx2*)(Pw + 128 * ln + ((32 * n + 8 * g) ^ swz)) = wq;
        }

        // ---- PV + l accumulation (P wave-private; same-wave DS in-order) ----
        #pragma unroll
        for (int kk = 0; kk < 2; ++kk) {
            bf16x8 vfv[4];
            #pragma unroll
            for (int n = 0; n < 4; ++n) {
                int row  = 16 * n + ln;                 // row&7 == ln&7
                int phys = 8 * sub + ((4 * kk + g) ^ (ln & 7));
                vfv[n] = *(const bf16x8*)&Vs[row * 128 + phys * 8];
            }
            bf16x8 pa = *(const bf16x8*)(Pw + 128 * ln + ((64 * kk + 16 * g) ^ swz));
            __builtin_amdgcn_s_setprio(1);
            #pragma unroll
            for (int n = 0; n < 4; ++n) O[n] = MFMA16(pa, vfv[n], O[n]);
            lacc = MFMA16(pa, onesf, lacc);
            __builtin_amdgcn_s_setprio(0);
        }
    };

    for (int tt = 0; tt < L_ / 128; ++tt) {
        stage(tt);
        __syncthreads();    // drains vmcnt(0): tile tt fully in LDS, all waves
        process(0);
        process(1);
        __syncthreads();    // all waves done reading before next stage
    }

    // epilogue: lacc[r] IS l for q=4g+r; normalize, write bf16 ao
    const int b = bh >> 4, hh = bh & 15;
    #pragma unroll
    for (int r = 0; r < 4; ++r) {
        float inv = 1.0f / lacc[r];
        int ql = q0 + 4 * g + r;
        ushort_t* dst = ao + ((size_t)(b * L_ + ql)) * D_ + hh * 64;
        #pragma unroll
        for (int n = 0; n < 4; ++n)
            dst[16 * n + ln] = f2bf(O[n][r] * inv);
    }
}

// ---------------------------------------------------------------------------
extern "C" void kernel_launch(void* const* d_in, const int* in_sizes, int n_in,
                              void* d_out, int out_size, void* d_ws, size_t ws_size,
                              hipStream_t stream)
{
    const float* x    = (const float*)d_in[0];
    const float* Wqkv = (const float*)d_in[1];
    const float* Wo   = (const float*)d_in[2];
    float* out = (float*)d_out;

    char* ws = (char*)d_ws;                               // 64 MB layout:
    ushort_t* xb  = (ushort_t*)(ws);                      // [0,8M)   x bf16; later ao
    ushort_t* wqt = (ushort_t*)(ws + ((size_t) 8 << 20)); // [8,14M)  Wqkv^T bf16
    ushort_t* wot = (ushort_t*)(ws + ((size_t)14 << 20)); // [14,16M) Wo^T bf16
    ushort_t* qR  = (ushort_t*)(ws + ((size_t)16 << 20)); // [16,24M) q rope'd (from GEMM)
    ushort_t* kR  = (ushort_t*)(ws + ((size_t)24 << 20)); // [24,32M) k rope'd (from GEMM)
    ushort_t* vt  = (ushort_t*)(ws + ((size_t)32 << 20)); // [32,40M) v^T (from GEMM)
    ushort_t* ao  = xb;                                   // alias (xb dead post-gemm)

    prep<<<3072, 256, 0, stream>>>(x, Wqkv, Wo, xb, wqt, wot);
    bgemm<1, 64, N1_/128, 1536><<<1536, 256, 0, stream>>>(xb, wqt, nullptr, qR, kR, vt);
    attn_mfma<<<512, 512, 0, stream>>>(qR, kR, vt, ao);
    bgemm<0, 64, D_/128, 512><<<512, 256, 0, stream>>>(ao, wot, out, nullptr, nullptr, nullptr);
}

// Round 21
// 113.075 us; speedup vs baseline: 1.2114x; 1.0096x over previous
//
#include <hip/hip_runtime.h>
#include <hip/hip_bf16.h>

#define B_  2
#define L_  2048
#define D_  1024
#define H_  16
#define DH_ 64
#define M_  (B_*L_)     // 4096
#define N1_ (3*D_)      // 3072

#define QSCALE (0.125f * 1.44269504088896340736f)   // 1/sqrt(64) * log2(e)

typedef __bf16 bf16x8 __attribute__((ext_vector_type(8)));
typedef float  f32x4  __attribute__((ext_vector_type(4)));
typedef unsigned short ushort_t;
typedef unsigned short ushort8_t __attribute__((ext_vector_type(8)));
typedef unsigned int   uintx2    __attribute__((ext_vector_type(2)));

#define MFMA16(a,b,c) __builtin_amdgcn_mfma_f32_16x16x32_bf16((a),(b),(c),0,0,0)

__device__ __forceinline__ float4 ld4(const float* p) { return *(const float4*)p; }

__device__ __forceinline__ ushort_t f2bf(float f) {
    union { float f; unsigned int u; } v; v.f = f;
    unsigned int r = (v.u + 0x7FFFu + ((v.u >> 16) & 1u)) >> 16;
    return (ushort_t)r;
}
__device__ __forceinline__ float bf2f(ushort_t u) {
    union { unsigned int u; float f; } v; v.u = ((unsigned int)u) << 16;
    return v.f;
}
// v_exp_f32 computes 2^x
__device__ __forceinline__ float exp2_(float x) {
    float r; asm("v_exp_f32 %0, %1" : "=v"(r) : "v"(x)); return r;
}
// hardware trig: input in REVOLUTIONS, reduce with v_fract first (ISA §3)
__device__ __forceinline__ float fract_(float x) {
    float r; asm("v_fract_f32 %0, %1" : "=v"(r) : "v"(x)); return r;
}
__device__ __forceinline__ float sin_rev(float x) {
    float r; asm("v_sin_f32 %0, %1" : "=v"(r) : "v"(x)); return r;
}
__device__ __forceinline__ float cos_rev(float x) {
    float r; asm("v_cos_f32 %0, %1" : "=v"(r) : "v"(x)); return r;
}
// packed f32 pair -> bf16 pair (lo = a, hi = b), RNE (same as f2bf)
__device__ __forceinline__ unsigned cvtpk(float a, float b) {
    unsigned r; asm("v_cvt_pk_bf16_f32 %0, %1, %2" : "=v"(r) : "v"(a), "v"(b)); return r;
}
// pull float from lane (byte_addr = src_lane*4)
__device__ __forceinline__ float bperm_f(int byte_addr, float v) {
    union { float f; int i; } u; u.f = v;
    u.i = __builtin_amdgcn_ds_bpermute(byte_addr, u.i);
    return u.f;
}
// async global->LDS, 16B per lane; LDS dest = wave-uniform base + lane*16
__device__ __forceinline__ void gload16(const ushort_t* g, ushort_t* l) {
    __builtin_amdgcn_global_load_lds(
        (const __attribute__((address_space(1))) unsigned int*)g,
        (__attribute__((address_space(3))) unsigned int*)l, 16, 0, 0);
}

// ---------------------------------------------------------------------------
// Fused prep: blocks [0,2048) x fp32->bf16; [2048,2816) Wqkv^T; [2816,3072) Wo^T
// ---------------------------------------------------------------------------
__global__ __launch_bounds__(256)
void prep(const float* __restrict__ x, const float* __restrict__ Wqkv,
          const float* __restrict__ Wo,
          ushort_t* __restrict__ xb, ushort_t* __restrict__ wqt,
          ushort_t* __restrict__ wot)
{
    __shared__ float vs[64][65];
    const int bid = blockIdx.x, t = threadIdx.x;
    if (bid < 2048) {
        int i = (bid * 256 + t) * 8;
        float4 a = ld4(x + i), b = ld4(x + i + 4);
        ushort8_t o;
        o[0] = f2bf(a.x); o[1] = f2bf(a.y); o[2] = f2bf(a.z); o[3] = f2bf(a.w);
        o[4] = f2bf(b.x); o[5] = f2bf(b.y); o[6] = f2bf(b.z); o[7] = f2bf(b.w);
        *(ushort8_t*)(xb + i) = o;
        return;
    }
    const float* in; ushort_t* out; int nt, kt, N;
    if (bid < 2048 + 768) {
        in = Wqkv; out = wqt; N = N1_;
        nt = (bid - 2048) % 48; kt = (bid - 2048) / 48;
    } else {
        in = Wo; out = wot; N = D_;
        nt = (bid - 2816) % 16; kt = (bid - 2816) / 16;
    }
    #pragma unroll
    for (int i = 0; i < 4; ++i) {
        int idx = t + 256 * i;
        int row = idx >> 4, c4 = idx & 15;
        float4 x4 = ld4(in + (size_t)(kt * 64 + row) * N + nt * 64 + c4 * 4);
        vs[row][c4*4+0] = x4.x; vs[row][c4*4+1] = x4.y;
        vs[row][c4*4+2] = x4.z; vs[row][c4*4+3] = x4.w;
    }
    __syncthreads();
    #pragma unroll
    for (int i = 0; i < 16; ++i) {
        int idx = t + 256 * i;
        int nc = idx >> 6, kc = idx & 63;
        out[(size_t)(nt * 64 + nc) * 1024 + kt * 64 + kc] = f2bf(vs[kc][nc]);
    }
}

// ---------------------------------------------------------------------------
// bf16 MFMA GEMM, m97 structure, tile BM x 128 (unchanged from R20).
// ---------------------------------------------------------------------------
template<int EPI, int BM, int NXB, int NWG>
__global__ __launch_bounds__(256)
void bgemm(const ushort_t* __restrict__ A, const ushort_t* __restrict__ Bt,
           float* __restrict__ Cf,
           ushort_t* __restrict__ Qo, ushort_t* __restrict__ Ko, ushort_t* __restrict__ Vo)
{
    constexpr int K  = 1024;
    constexpr int MI = BM / 32;             // acc rows per wave (4 or 2)
    __shared__ ushort_t As[BM * 64];
    __shared__ ushort_t Bs[128 * 64];
    const int t  = threadIdx.x;
    const int l  = t & 63, w = t >> 6;
    const int g  = l >> 4, ln = l & 15;
    const int wr = w >> 1, wc = w & 1;
    const int bid = blockIdx.x;
    const int lid = (bid & 7) * (NWG / 8) + (bid >> 3);
    const int m0 = (lid / NXB) * BM, n0 = (lid % NXB) * 128;

    const int srow = w * 8 + (l >> 3);
    const int sch  = (l & 7) ^ (l >> 3);
    const ushort_t* Ag = A  + ((size_t)(m0 + srow)) * K + sch * 8;
    const ushort_t* Bg = Bt + ((size_t)(n0 + srow)) * K + sch * 8;

    f32x4 acc[MI][4];
    #pragma unroll
    for (int mi = 0; mi < MI; ++mi)
        #pragma unroll
        for (int nj = 0; nj < 4; ++nj) acc[mi][nj] = f32x4{0.f, 0.f, 0.f, 0.f};

    for (int kt = 0; kt < K / 64; ++kt) {
        #pragma unroll
        for (int i = 0; i < BM / 32; ++i)
            gload16(Ag + (size_t)i * 32 * K + kt * 64, &As[i * 2048 + w * 512]);
        #pragma unroll
        for (int i = 0; i < 4; ++i)
            gload16(Bg + (size_t)i * 32 * K + kt * 64, &Bs[i * 2048 + w * 512]);
        __syncthreads();

        #pragma unroll
        for (int kk = 0; kk < 2; ++kk) {
            bf16x8 af[MI], bfv[4];
            #pragma unroll
            for (int mi = 0; mi < MI; ++mi) {
                int row  = (BM / 2) * wr + 16 * mi + ln;
                int phys = (4 * kk + g) ^ (ln & 7);
                af[mi] = *(const bf16x8*)&As[row * 64 + phys * 8];
            }
            #pragma unroll
            for (int nj = 0; nj < 4; ++nj) {
                int row  = 64 * wc + 16 * nj + ln;
                int phys = (4 * kk + g) ^ (ln & 7);
                bfv[nj] = *(const bf16x8*)&Bs[row * 64 + phys * 8];
            }
            #pragma unroll
            for (int mi = 0; mi < MI; ++mi)
                #pragma unroll
                for (int nj = 0; nj < 4; ++nj)
                    acc[mi][nj] = MFMA16(af[mi], bfv[nj], acc[mi][nj]);
        }
        __syncthreads();   // final iteration: all LDS reads done -> As reusable
    }

    if (EPI == 0) {
        #pragma unroll
        for (int mi = 0; mi < MI; ++mi) {
            #pragma unroll
            for (int nj = 0; nj < 4; ++nj) {
                int n = n0 + 64 * wc + 16 * nj + ln;
                #pragma unroll
                for (int r = 0; r < 4; ++r) {
                    int m = m0 + (BM / 2) * wr + 16 * mi + 4 * g + r;
                    Cf[(size_t)m * D_ + n] = acc[mi][nj][r];
                }
            }
        }
    } else {
        // all four nj share one 64-column block -> same (which, head)
        const int nb    = n0 + 64 * wc;
        const int which = nb >> 10;
        const int h     = (nb >> 6) & (H_ - 1);
        if (which == 2) {
            // V: transposed scatter [bh][d][L] via wave-private LDS transpose.
            // Padded rows (stride 16*MI+4 ushorts) spread banks; no XOR.
            constexpr int RW = 16 * MI + 4;
            ushort_t* epi = As + (size_t)w * (16 * RW);
            const int mb = m0 + (BM / 2) * wr;     // wave's m base (MI*16 rows)
            const int bb = mb >> 11;
            const int llb = mb & (L_ - 1);
            #pragma unroll
            for (int nj = 0; nj < 4; ++nj) {
                #pragma unroll
                for (int mi = 0; mi < MI; ++mi) {
                    uintx2 wq;
                    wq[0] = cvtpk(acc[mi][nj][0], acc[mi][nj][1]);
                    wq[1] = cvtpk(acc[mi][nj][2], acc[mi][nj][3]);
                    *(uintx2*)&epi[ln * RW + (4 * mi + g) * 4] = wq;
                }
                // same-wave DS in-order: read back transposed, 16B chunks
                if (MI == 4) {
                    #pragma unroll
                    for (int p = 0; p < 2; ++p) {
                        int rr = (l >> 3) + 8 * p;     // 0..15 (n_local)
                        int c  = l & 7;                // 8 m-values at 8c
                        ushort8_t v8 = *(const ushort8_t*)&epi[rr * RW + 8 * c];
                        *(ushort8_t*)&Vo[((size_t)(bb * H_ + h) * DH_ + 16 * nj + rr) * L_
                                         + llb + 8 * c] = v8;
                    }
                } else {
                    int rr = l >> 2;                   // 0..15
                    int c  = l & 3;                    // 8 m-values at 8c
                    ushort8_t v8 = *(const ushort8_t*)&epi[rr * RW + 8 * c];
                    *(ushort8_t*)&Vo[((size_t)(bb * H_ + h) * DH_ + 16 * nj + rr) * L_
                                     + llb + 8 * c] = v8;
                }
            }
        } else {                    // Q or K: fused RoPE (pairs nj & nj+2)
            ushort_t* base = (which == 0) ? Qo : Ko;
            const float scale = (which == 0) ? QSCALE : 1.0f;
            const float invr0 = exp2_(-(float)ln        * 0.41524101186f) * 0.15915494310f;
            const float invr1 = exp2_(-(float)(16 + ln) * 0.41524101186f) * 0.15915494310f;
            #pragma unroll
            for (int mi = 0; mi < MI; ++mi) {
                #pragma unroll
                for (int r = 0; r < 4; ++r) {
                    int m = m0 + (BM / 2) * wr + 16 * mi + 4 * g + r;
                    int b = m >> 11, ll = m & (L_ - 1);
                    float rv0 = fract_((float)ll * invr0);
                    float rv1 = fract_((float)ll * invr1);
                    float s0 = sin_rev(rv0), c0 = cos_rev(rv0);
                    float s1 = sin_rev(rv1), c1 = cos_rev(rv1);
                    size_t rb = ((size_t)(b * H_ + h) * L_ + ll) * DH_;
                    float a1 = acc[mi][0][r], a2 = acc[mi][2][r];
                    base[rb + ln]      = f2bf((a1 * c0 - a2 * s0) * scale);
                    base[rb + ln + 32] = f2bf((a2 * c0 + a1 * s0) * scale);
                    float b1 = acc[mi][1][r], b2 = acc[mi][3][r];
                    base[rb + 16 + ln]      = f2bf((b1 * c1 - b2 * s1) * scale);
                    base[rb + 16 + ln + 32] = f2bf((b2 * c1 + b1 * s1) * scale);
                }
            }
        }
    }
}

// ---------------------------------------------------------------------------
// Flash attention (R16 structure, KVBLK=256): 512-thread blocks, 8 waves x
// 16 q sharing one K/V stage per 256-key tile -> 8 tiles, HALF the barrier/
// drain points of R16 (attn is ~81% LDS-pipe-bound; barriers are the gap).
// LDS 80KB; occupancy grid-capped at 2 blocks/CU either way. Numerics
// bit-identical (subs 0..3 process keys in the same order).
// Layouts: A: lane holds A[ln][32kk+8g+j]; B: lane holds Bt[ln][32kk+8g+j];
//          D: lane reg r -> D[4g+r][ln]   (g=lane>>4, ln=lane&15)
// ---------------------------------------------------------------------------
__global__ __launch_bounds__(512)
void attn_mfma(const ushort_t* __restrict__ qb, const ushort_t* __restrict__ kb,
               const ushort_t* __restrict__ vt, ushort_t* __restrict__ ao)
{
    __shared__ ushort_t Ks[256 * 64];       // [key][d], 128B rows, swizzled
    __shared__ ushort_t Vs[64 * 256];       // [d][key], 512B rows, swizzled
    __shared__ ushort_t Ps[8][16 * 64];     // per-wave P [16 q][64 key], swizzled

    const int t    = threadIdx.x;
    const int lane = t & 63, wv = t >> 6;   // wv in 0..7
    const int g    = lane >> 4, ln = lane & 15;
    const int bid  = blockIdx.x;            // 512 blocks
    const int lid  = (bid & 7) * 64 + (bid >> 3);
    const int bh   = lid >> 4;              // qb-fast: 16 consecutive lids/head
    const int q0   = (lid & 15) * 128 + wv * 16;

    // Q fragments: rows q0+ln
    const ushort_t* qpA = qb + ((size_t)bh * L_ + q0 + ln) * DH_;
    bf16x8 qf0 = *(const bf16x8*)(qpA + 8 * g);
    bf16x8 qf1 = *(const bf16x8*)(qpA + 32 + 8 * g);

    const ushort_t* kp = kb + (size_t)bh * L_ * DH_;
    const ushort_t* vp = vt + (size_t)bh * DH_ * L_;

    // ones B-fragment for the l-accumulating MFMA
    union { ushort8_t u; bf16x8 v; } onesu;
    #pragma unroll
    for (int j = 0; j < 8; ++j) onesu.u[j] = 0x3F80;   // bf16 1.0
    const bf16x8 onesf = onesu.v;

    // K staging: 8 waves x 4 issues x 8 rows = 256 rows (row&7 = lane>>3)
    const int krow8 = lane >> 3;
    const int ksch  = (lane & 7) ^ krow8;
    // V staging: 8 waves x 4 issues x 2 rows (512B each) = 64 d-rows;
    // lane covers row = base + (lane>>5), phys chunk pc = lane&31;
    // source logical chunk = (pc&24) | ((pc&7) ^ (row&7))  (XOR in low 3 bits)
    const int vrow2 = lane >> 5;            // 0..1 within the gload's row pair
    const int vpc   = lane & 31;

    char* Pw = (char*)&Ps[wv][0];
    const int swz = (ln & 7) << 4;

    f32x4 O[4], lacc;
    lacc = f32x4{0.f, 0.f, 0.f, 0.f};
    #pragma unroll
    for (int n = 0; n < 4; ++n) O[n] = f32x4{0.f, 0.f, 0.f, 0.f};
    float m_q = 0.f;                        // base-2 bias (defer-max)

    auto stage = [&](int tt) {
        #pragma unroll
        for (int i = 0; i < 4; ++i) {
            int row = 32 * wv + 8 * i + krow8;
            gload16(kp + ((size_t)(tt * 256 + row)) * 64 + ksch * 8,
                    &Ks[(32 * wv + 8 * i) * 64]);
        }
        #pragma unroll
        for (int i = 0; i < 4; ++i) {
            int row = 8 * wv + 2 * i + vrow2;
            int sc  = (vpc & 24) | ((vpc & 7) ^ (row & 7));
            gload16(vp + ((size_t)row) * L_ + tt * 256 + sc * 8,
                    &Vs[(8 * wv + 2 * i) * 256]);
        }
    };

    auto process = [&](int sub) {
        // ---- swapped QK^T, acc pre-biased by -m ----
        f32x4 S[4];
        #pragma unroll
        for (int n = 0; n < 4; ++n)
            S[n] = f32x4{-m_q, -m_q, -m_q, -m_q};
        #pragma unroll
        for (int kk = 0; kk < 2; ++kk) {
            bf16x8 kfv[4];
            #pragma unroll
            for (int n = 0; n < 4; ++n) {
                int row  = 64 * sub + 16 * n + ln;      // row&7 == ln&7
                int phys = (4 * kk + g) ^ (ln & 7);
                kfv[n] = *(const bf16x8*)&Ks[row * 64 + phys * 8];
            }
            bf16x8 a = kk ? qf1 : qf0;
            __builtin_amdgcn_s_setprio(1);
            #pragma unroll
            for (int n = 0; n < 4; ++n) S[n] = MFMA16(kfv[n], a, S[n]);
            __builtin_amdgcn_s_setprio(0);
        }

        // ---- softmax (q = ln); S is already S_true - m ----
        float pmax;                         // lane-local max (16 values)
        {
            float a0 = fmaxf(fmaxf(S[0][0], S[0][1]), fmaxf(S[0][2], S[0][3]));
            float a1 = fmaxf(fmaxf(S[1][0], S[1][1]), fmaxf(S[1][2], S[1][3]));
            float a2 = fmaxf(fmaxf(S[2][0], S[2][1]), fmaxf(S[2][2], S[2][3]));
            float a3 = fmaxf(fmaxf(S[3][0], S[3][1]), fmaxf(S[3][2], S[3][3]));
            pmax = fmaxf(fmaxf(a0, a1), fmaxf(a2, a3));
        }
        // guard aggregates over ALL lanes -> lane-local max suffices here;
        // full row max (2 shuffles) only needed inside the rare branch.
        if (!__all(pmax <= 8.0f)) {
            pmax = fmaxf(pmax, __shfl_xor(pmax, 16));
            pmax = fmaxf(pmax, __shfl_xor(pmax, 32));
            m_q += pmax;
            float al = exp2_(-pmax);
            #pragma unroll
            for (int r = 0; r < 4; ++r) {
                float alr = bperm_f((4 * g + r) * 4, al);
                lacc[r] *= alr;
                #pragma unroll
                for (int n = 0; n < 4; ++n) O[n][r] *= alr;
            }
            #pragma unroll
            for (int n = 0; n < 4; ++n) S[n] = S[n] - pmax;
        }

        #pragma unroll
        for (int n = 0; n < 4; ++n) {
            float p0 = exp2_(S[n][0]);
            float p1 = exp2_(S[n][1]);
            float p2 = exp2_(S[n][2]);
            float p3 = exp2_(S[n][3]);
            uintx2 wq;
            wq[0] = cvtpk(p0, p1);
            wq[1] = cvtpk(p2, p3);
            *(uintx2*)(Pw + 128 * ln + ((32 * n + 8 * g) ^ swz)) = wq;
        }

        // ---- PV + l accumulation (P wave-private; same-wave DS in-order) ----
        #pragma unroll
        for (int kk = 0; kk < 2; ++kk) {
            bf16x8 vfv[4];
            #pragma unroll
            for (int n = 0; n < 4; ++n) {
                int row  = 16 * n + ln;                 // row&7 == ln&7
                int phys = 8 * sub + ((4 * kk + g) ^ (ln & 7));
                vfv[n] = *(const bf16x8*)&Vs[row * 256 + phys * 8];
            }
            bf16x8 pa = *(const bf16x8*)(Pw + 128 * ln + ((64 * kk + 16 * g) ^ swz));
            __builtin_amdgcn_s_setprio(1);
            #pragma unroll
            for (int n = 0; n < 4; ++n) O[n] = MFMA16(pa, vfv[n], O[n]);
            lacc = MFMA16(pa, onesf, lacc);
            __builtin_amdgcn_s_setprio(0);
        }
    };

    for (int tt = 0; tt < L_ / 256; ++tt) {
        stage(tt);
        __syncthreads();    // drains vmcnt(0): tile tt fully in LDS, all waves
        process(0);
        process(1);
        process(2);
        process(3);
        __syncthreads();    // all waves done reading before next stage
    }

    // epilogue: lacc[r] IS l for q=4g+r; normalize, write bf16 ao
    const int b = bh >> 4, hh = bh & 15;
    #pragma unroll
    for (int r = 0; r < 4; ++r) {
        float inv = 1.0f / lacc[r];
        int ql = q0 + 4 * g + r;
        ushort_t* dst = ao + ((size_t)(b * L_ + ql)) * D_ + hh * 64;
        #pragma unroll
        for (int n = 0; n < 4; ++n)
            dst[16 * n + ln] = f2bf(O[n][r] * inv);
    }
}

// ---------------------------------------------------------------------------
extern "C" void kernel_launch(void* const* d_in, const int* in_sizes, int n_in,
                              void* d_out, int out_size, void* d_ws, size_t ws_size,
                              hipStream_t stream)
{
    const float* x    = (const float*)d_in[0];
    const float* Wqkv = (const float*)d_in[1];
    const float* Wo   = (const float*)d_in[2];
    float* out = (float*)d_out;

    char* ws = (char*)d_ws;                               // 64 MB layout:
    ushort_t* xb  = (ushort_t*)(ws);                      // [0,8M)   x bf16; later ao
    ushort_t* wqt = (ushort_t*)(ws + ((size_t) 8 << 20)); // [8,14M)  Wqkv^T bf16
    ushort_t* wot = (ushort_t*)(ws + ((size_t)14 << 20)); // [14,16M) Wo^T bf16
    ushort_t* qR  = (ushort_t*)(ws + ((size_t)16 << 20)); // [16,24M) q rope'd (from GEMM)
    ushort_t* kR  = (ushort_t*)(ws + ((size_t)24 << 20)); // [24,32M) k rope'd (from GEMM)
    ushort_t* vt  = (ushort_t*)(ws + ((size_t)32 << 20)); // [32,40M) v^T (from GEMM)
    ushort_t* ao  = xb;                                   // alias (xb dead post-gemm)

    prep<<<3072, 256, 0, stream>>>(x, Wqkv, Wo, xb, wqt, wot);
    bgemm<1, 64, N1_/128, 1536><<<1536, 256, 0, stream>>>(xb, wqt, nullptr, qR, kR, vt);
    attn_mfma<<<512, 512, 0, stream>>>(qR, kR, vt, ao);
    bgemm<0, 64, D_/128, 512><<<512, 256, 0, stream>>>(ao, wot, out, nullptr, nullptr, nullptr);
}

// Round 22
// 112.073 us; speedup vs baseline: 1.2223x; 1.0089x over previous
//
#include <hip/hip_runtime.h>
#include <hip/hip_bf16.h>

#define B_  2
#define L_  2048
#define D_  1024
#define H_  16
#define DH_ 64
#define M_  (B_*L_)     // 4096
#define N1_ (3*D_)      // 3072

#define QSCALE (0.125f * 1.44269504088896340736f)   // 1/sqrt(64) * log2(e)

typedef __bf16 bf16x8 __attribute__((ext_vector_type(8)));
typedef float  f32x4  __attribute__((ext_vector_type(4)));
typedef unsigned short ushort_t;
typedef unsigned short ushort8_t __attribute__((ext_vector_type(8)));
typedef unsigned int   uintx2    __attribute__((ext_vector_type(2)));

#define MFMA16(a,b,c) __builtin_amdgcn_mfma_f32_16x16x32_bf16((a),(b),(c),0,0,0)

__device__ __forceinline__ float4 ld4(const float* p) { return *(const float4*)p; }

__device__ __forceinline__ ushort_t f2bf(float f) {
    union { float f; unsigned int u; } v; v.f = f;
    unsigned int r = (v.u + 0x7FFFu + ((v.u >> 16) & 1u)) >> 16;
    return (ushort_t)r;
}
__device__ __forceinline__ float bf2f(ushort_t u) {
    union { unsigned int u; float f; } v; v.u = ((unsigned int)u) << 16;
    return v.f;
}
// v_exp_f32 computes 2^x
__device__ __forceinline__ float exp2_(float x) {
    float r; asm("v_exp_f32 %0, %1" : "=v"(r) : "v"(x)); return r;
}
// hardware trig: input in REVOLUTIONS, reduce with v_fract first (ISA §3)
__device__ __forceinline__ float fract_(float x) {
    float r; asm("v_fract_f32 %0, %1" : "=v"(r) : "v"(x)); return r;
}
__device__ __forceinline__ float sin_rev(float x) {
    float r; asm("v_sin_f32 %0, %1" : "=v"(r) : "v"(x)); return r;
}
__device__ __forceinline__ float cos_rev(float x) {
    float r; asm("v_cos_f32 %0, %1" : "=v"(r) : "v"(x)); return r;
}
// packed f32 pair -> bf16 pair (lo = a, hi = b), RNE (same as f2bf)
__device__ __forceinline__ unsigned cvtpk(float a, float b) {
    unsigned r; asm("v_cvt_pk_bf16_f32 %0, %1, %2" : "=v"(r) : "v"(a), "v"(b)); return r;
}
// pull float from lane (byte_addr = src_lane*4)
__device__ __forceinline__ float bperm_f(int byte_addr, float v) {
    union { float f; int i; } u; u.f = v;
    u.i = __builtin_amdgcn_ds_bpermute(byte_addr, u.i);
    return u.f;
}
// async global->LDS, 16B per lane; LDS dest = wave-uniform base + lane*16
__device__ __forceinline__ void gload16(const ushort_t* g, ushort_t* l) {
    __builtin_amdgcn_global_load_lds(
        (const __attribute__((address_space(1))) unsigned int*)g,
        (__attribute__((address_space(3))) unsigned int*)l, 16, 0, 0);
}

// ---------------------------------------------------------------------------
// Fused prep: blocks [0,2048) x fp32->bf16; [2048,2816) Wqkv^T; [2816,3072) Wo^T
// ---------------------------------------------------------------------------
__global__ __launch_bounds__(256)
void prep(const float* __restrict__ x, const float* __restrict__ Wqkv,
          const float* __restrict__ Wo,
          ushort_t* __restrict__ xb, ushort_t* __restrict__ wqt,
          ushort_t* __restrict__ wot)
{
    __shared__ float vs[64][65];
    const int bid = blockIdx.x, t = threadIdx.x;
    if (bid < 2048) {
        int i = (bid * 256 + t) * 8;
        float4 a = ld4(x + i), b = ld4(x + i + 4);
        ushort8_t o;
        o[0] = f2bf(a.x); o[1] = f2bf(a.y); o[2] = f2bf(a.z); o[3] = f2bf(a.w);
        o[4] = f2bf(b.x); o[5] = f2bf(b.y); o[6] = f2bf(b.z); o[7] = f2bf(b.w);
        *(ushort8_t*)(xb + i) = o;
        return;
    }
    const float* in; ushort_t* out; int nt, kt, N;
    if (bid < 2048 + 768) {
        in = Wqkv; out = wqt; N = N1_;
        nt = (bid - 2048) % 48; kt = (bid - 2048) / 48;
    } else {
        in = Wo; out = wot; N = D_;
        nt = (bid - 2816) % 16; kt = (bid - 2816) / 16;
    }
    #pragma unroll
    for (int i = 0; i < 4; ++i) {
        int idx = t + 256 * i;
        int row = idx >> 4, c4 = idx & 15;
        float4 x4 = ld4(in + (size_t)(kt * 64 + row) * N + nt * 64 + c4 * 4);
        vs[row][c4*4+0] = x4.x; vs[row][c4*4+1] = x4.y;
        vs[row][c4*4+2] = x4.z; vs[row][c4*4+3] = x4.w;
    }
    __syncthreads();
    #pragma unroll
    for (int i = 0; i < 16; ++i) {
        int idx = t + 256 * i;
        int nc = idx >> 6, kc = idx & 63;
        out[(size_t)(nt * 64 + nc) * 1024 + kt * 64 + kc] = f2bf(vs[kc][nc]);
    }
}

// ---------------------------------------------------------------------------
// bf16 MFMA GEMM, m97 structure, tile BM x BN. 1D grid of NWG blocks with
// XCD-chunked swizzle (NWG%8==0): lid = (bid&7)*(NWG/8) + bid>>3, n fast.
// EPI 0: fp32 C (any BM/BN). EPI 1 (requires BN=128): QKV scatter, fused
// RoPE, V transposed through a wave-private padded-row LDS micro-transpose.
// ---------------------------------------------------------------------------
template<int EPI, int BM, int BN, int NXB, int NWG>
__global__ __launch_bounds__(256)
void bgemm(const ushort_t* __restrict__ A, const ushort_t* __restrict__ Bt,
           float* __restrict__ Cf,
           ushort_t* __restrict__ Qo, ushort_t* __restrict__ Ko, ushort_t* __restrict__ Vo)
{
    constexpr int K  = 1024;
    constexpr int MI = BM / 32;             // acc row-blocks per wave
    constexpr int NJ = BN / 32;             // acc col-blocks per wave
    __shared__ ushort_t As[BM * 64];
    __shared__ ushort_t Bs[BN * 64];
    const int t  = threadIdx.x;
    const int l  = t & 63, w = t >> 6;
    const int g  = l >> 4, ln = l & 15;
    const int wr = w >> 1, wc = w & 1;
    const int bid = blockIdx.x;
    const int lid = (bid & 7) * (NWG / 8) + (bid >> 3);
    const int m0 = (lid / NXB) * BM, n0 = (lid % NXB) * BN;

    const int srow = w * 8 + (l >> 3);
    const int sch  = (l & 7) ^ (l >> 3);
    const ushort_t* Ag = A  + ((size_t)(m0 + srow)) * K + sch * 8;
    const ushort_t* Bg = Bt + ((size_t)(n0 + srow)) * K + sch * 8;

    f32x4 acc[MI][NJ];
    #pragma unroll
    for (int mi = 0; mi < MI; ++mi)
        #pragma unroll
        for (int nj = 0; nj < NJ; ++nj) acc[mi][nj] = f32x4{0.f, 0.f, 0.f, 0.f};

    for (int kt = 0; kt < K / 64; ++kt) {
        #pragma unroll
        for (int i = 0; i < BM / 32; ++i)
            gload16(Ag + (size_t)i * 32 * K + kt * 64, &As[i * 2048 + w * 512]);
        #pragma unroll
        for (int i = 0; i < BN / 32; ++i)
            gload16(Bg + (size_t)i * 32 * K + kt * 64, &Bs[i * 2048 + w * 512]);
        __syncthreads();

        #pragma unroll
        for (int kk = 0; kk < 2; ++kk) {
            bf16x8 af[MI], bfv[NJ];
            #pragma unroll
            for (int mi = 0; mi < MI; ++mi) {
                int row  = (BM / 2) * wr + 16 * mi + ln;
                int phys = (4 * kk + g) ^ (ln & 7);
                af[mi] = *(const bf16x8*)&As[row * 64 + phys * 8];
            }
            #pragma unroll
            for (int nj = 0; nj < NJ; ++nj) {
                int row  = (BN / 2) * wc + 16 * nj + ln;
                int phys = (4 * kk + g) ^ (ln & 7);
                bfv[nj] = *(const bf16x8*)&Bs[row * 64 + phys * 8];
            }
            #pragma unroll
            for (int mi = 0; mi < MI; ++mi)
                #pragma unroll
                for (int nj = 0; nj < NJ; ++nj)
                    acc[mi][nj] = MFMA16(af[mi], bfv[nj], acc[mi][nj]);
        }
        __syncthreads();   // final iteration: all LDS reads done -> As reusable
    }

    if (EPI == 0) {
        #pragma unroll
        for (int mi = 0; mi < MI; ++mi) {
            #pragma unroll
            for (int nj = 0; nj < NJ; ++nj) {
                int n = n0 + (BN / 2) * wc + 16 * nj + ln;
                #pragma unroll
                for (int r = 0; r < 4; ++r) {
                    int m = m0 + (BM / 2) * wr + 16 * mi + 4 * g + r;
                    Cf[(size_t)m * D_ + n] = acc[mi][nj][r];
                }
            }
        }
    } else {
        // BN==128 path: all four nj share one 64-col block -> same (which, head)
        const int nb    = n0 + 64 * wc;
        const int which = nb >> 10;
        const int h     = (nb >> 6) & (H_ - 1);
        if (which == 2) {
            // V: transposed scatter [bh][d][L] via wave-private LDS transpose.
            // Padded rows (stride 16*MI+4 ushorts) spread banks; no XOR.
            constexpr int RW = 16 * MI + 4;
            ushort_t* epi = As + (size_t)w * (16 * RW);
            const int mb = m0 + (BM / 2) * wr;     // wave's m base (MI*16 rows)
            const int bb = mb >> 11;
            const int llb = mb & (L_ - 1);
            #pragma unroll
            for (int nj = 0; nj < NJ; ++nj) {
                #pragma unroll
                for (int mi = 0; mi < MI; ++mi) {
                    uintx2 wq;
                    wq[0] = cvtpk(acc[mi][nj][0], acc[mi][nj][1]);
                    wq[1] = cvtpk(acc[mi][nj][2], acc[mi][nj][3]);
                    *(uintx2*)&epi[ln * RW + (4 * mi + g) * 4] = wq;
                }
                // same-wave DS in-order: read back transposed, 16B chunks
                if (MI == 4) {
                    #pragma unroll
                    for (int p = 0; p < 2; ++p) {
                        int rr = (l >> 3) + 8 * p;     // 0..15 (n_local)
                        int c  = l & 7;                // 8 m-values at 8c
                        ushort8_t v8 = *(const ushort8_t*)&epi[rr * RW + 8 * c];
                        *(ushort8_t*)&Vo[((size_t)(bb * H_ + h) * DH_ + 16 * nj + rr) * L_
                                         + llb + 8 * c] = v8;
                    }
                } else {
                    int rr = l >> 2;                   // 0..15
                    int c  = l & 3;                    // 8 m-values at 8c
                    ushort8_t v8 = *(const ushort8_t*)&epi[rr * RW + 8 * c];
                    *(ushort8_t*)&Vo[((size_t)(bb * H_ + h) * DH_ + 16 * nj + rr) * L_
                                     + llb + 8 * c] = v8;
                }
            }
        } else {                    // Q or K: fused RoPE (pairs nj & nj+2)
            ushort_t* base = (which == 0) ? Qo : Ko;
            const float scale = (which == 0) ? QSCALE : 1.0f;
            const float invr0 = exp2_(-(float)ln        * 0.41524101186f) * 0.15915494310f;
            const float invr1 = exp2_(-(float)(16 + ln) * 0.41524101186f) * 0.15915494310f;
            #pragma unroll
            for (int mi = 0; mi < MI; ++mi) {
                #pragma unroll
                for (int r = 0; r < 4; ++r) {
                    int m = m0 + (BM / 2) * wr + 16 * mi + 4 * g + r;
                    int b = m >> 11, ll = m & (L_ - 1);
                    float rv0 = fract_((float)ll * invr0);
                    float rv1 = fract_((float)ll * invr1);
                    float s0 = sin_rev(rv0), c0 = cos_rev(rv0);
                    float s1 = sin_rev(rv1), c1 = cos_rev(rv1);
                    size_t rb = ((size_t)(b * H_ + h) * L_ + ll) * DH_;
                    float a1 = acc[mi][0][r], a2 = acc[mi][2][r];
                    base[rb + ln]      = f2bf((a1 * c0 - a2 * s0) * scale);
                    base[rb + ln + 32] = f2bf((a2 * c0 + a1 * s0) * scale);
                    float b1 = acc[mi][1][r], b2 = acc[mi][3][r];
                    base[rb + 16 + ln]      = f2bf((b1 * c1 - b2 * s1) * scale);
                    base[rb + 16 + ln + 32] = f2bf((b2 * c1 + b1 * s1) * scale);
                }
            }
        }
    }
}

// ---------------------------------------------------------------------------
// Flash attention (R21 verified: KVBLK=256): 512-thread blocks, 8 waves x
// 16 q sharing one K/V stage per 256-key tile; 8 tiles. ~92% of the LDS-
// operand-delivery bound for this structure (further gains need >=32q/wave
// state, which exceeds the VGPR budget - closed after R13/R17/R18).
// Layouts: A: lane holds A[ln][32kk+8g+j]; B: lane holds Bt[ln][32kk+8g+j];
//          D: lane reg r -> D[4g+r][ln]   (g=lane>>4, ln=lane&15)
// ---------------------------------------------------------------------------
__global__ __launch_bounds__(512)
void attn_mfma(const ushort_t* __restrict__ qb, const ushort_t* __restrict__ kb,
               const ushort_t* __restrict__ vt, ushort_t* __restrict__ ao)
{
    __shared__ ushort_t Ks[256 * 64];       // [key][d], 128B rows, swizzled
    __shared__ ushort_t Vs[64 * 256];       // [d][key], 512B rows, swizzled
    __shared__ ushort_t Ps[8][16 * 64];     // per-wave P [16 q][64 key], swizzled

    const int t    = threadIdx.x;
    const int lane = t & 63, wv = t >> 6;   // wv in 0..7
    const int g    = lane >> 4, ln = lane & 15;
    const int bid  = blockIdx.x;            // 512 blocks
    const int lid  = (bid & 7) * 64 + (bid >> 3);
    const int bh   = lid >> 4;              // qb-fast: 16 consecutive lids/head
    const int q0   = (lid & 15) * 128 + wv * 16;

    // Q fragments: rows q0+ln
    const ushort_t* qpA = qb + ((size_t)bh * L_ + q0 + ln) * DH_;
    bf16x8 qf0 = *(const bf16x8*)(qpA + 8 * g);
    bf16x8 qf1 = *(const bf16x8*)(qpA + 32 + 8 * g);

    const ushort_t* kp = kb + (size_t)bh * L_ * DH_;
    const ushort_t* vp = vt + (size_t)bh * DH_ * L_;

    // ones B-fragment for the l-accumulating MFMA
    union { ushort8_t u; bf16x8 v; } onesu;
    #pragma unroll
    for (int j = 0; j < 8; ++j) onesu.u[j] = 0x3F80;   // bf16 1.0
    const bf16x8 onesf = onesu.v;

    // K staging: 8 waves x 4 issues x 8 rows = 256 rows (row&7 = lane>>3)
    const int krow8 = lane >> 3;
    const int ksch  = (lane & 7) ^ krow8;
    // V staging: 8 waves x 4 issues x 2 rows (512B each) = 64 d-rows;
    // source logical chunk = (pc&24) | ((pc&7) ^ (row&7))
    const int vrow2 = lane >> 5;
    const int vpc   = lane & 31;

    char* Pw = (char*)&Ps[wv][0];
    const int swz = (ln & 7) << 4;

    f32x4 O[4], lacc;
    lacc = f32x4{0.f, 0.f, 0.f, 0.f};
    #pragma unroll
    for (int n = 0; n < 4; ++n) O[n] = f32x4{0.f, 0.f, 0.f, 0.f};
    float m_q = 0.f;                        // base-2 bias (defer-max)

    auto stage = [&](int tt) {
        #pragma unroll
        for (int i = 0; i < 4; ++i) {
            int row = 32 * wv + 8 * i + krow8;
            gload16(kp + ((size_t)(tt * 256 + row)) * 64 + ksch * 8,
                    &Ks[(32 * wv + 8 * i) * 64]);
        }
        #pragma unroll
        for (int i = 0; i < 4; ++i) {
            int row = 8 * wv + 2 * i + vrow2;
            int sc  = (vpc & 24) | ((vpc & 7) ^ (row & 7));
            gload16(vp + ((size_t)row) * L_ + tt * 256 + sc * 8,
                    &Vs[(8 * wv + 2 * i) * 256]);
        }
    };

    auto process = [&](int sub) {
        // ---- swapped QK^T, acc pre-biased by -m ----
        f32x4 S[4];
        #pragma unroll
        for (int n = 0; n < 4; ++n)
            S[n] = f32x4{-m_q, -m_q, -m_q, -m_q};
        #pragma unroll
        for (int kk = 0; kk < 2; ++kk) {
            bf16x8 kfv[4];
            #pragma unroll
            for (int n = 0; n < 4; ++n) {
                int row  = 64 * sub + 16 * n + ln;      // row&7 == ln&7
                int phys = (4 * kk + g) ^ (ln & 7);
                kfv[n] = *(const bf16x8*)&Ks[row * 64 + phys * 8];
            }
            bf16x8 a = kk ? qf1 : qf0;
            __builtin_amdgcn_s_setprio(1);
            #pragma unroll
            for (int n = 0; n < 4; ++n) S[n] = MFMA16(kfv[n], a, S[n]);
            __builtin_amdgcn_s_setprio(0);
        }

        // ---- softmax (q = ln); S is already S_true - m ----
        float pmax;                         // lane-local max (16 values)
        {
            float a0 = fmaxf(fmaxf(S[0][0], S[0][1]), fmaxf(S[0][2], S[0][3]));
            float a1 = fmaxf(fmaxf(S[1][0], S[1][1]), fmaxf(S[1][2], S[1][3]));
            float a2 = fmaxf(fmaxf(S[2][0], S[2][1]), fmaxf(S[2][2], S[2][3]));
            float a3 = fmaxf(fmaxf(S[3][0], S[3][1]), fmaxf(S[3][2], S[3][3]));
            pmax = fmaxf(fmaxf(a0, a1), fmaxf(a2, a3));
        }
        if (!__all(pmax <= 8.0f)) {
            pmax = fmaxf(pmax, __shfl_xor(pmax, 16));
            pmax = fmaxf(pmax, __shfl_xor(pmax, 32));
            m_q += pmax;
            float al = exp2_(-pmax);
            #pragma unroll
            for (int r = 0; r < 4; ++r) {
                float alr = bperm_f((4 * g + r) * 4, al);
                lacc[r] *= alr;
                #pragma unroll
                for (int n = 0; n < 4; ++n) O[n][r] *= alr;
            }
            #pragma unroll
            for (int n = 0; n < 4; ++n) S[n] = S[n] - pmax;
        }

        #pragma unroll
        for (int n = 0; n < 4; ++n) {
            float p0 = exp2_(S[n][0]);
            float p1 = exp2_(S[n][1]);
            float p2 = exp2_(S[n][2]);
            float p3 = exp2_(S[n][3]);
            uintx2 wq;
            wq[0] = cvtpk(p0, p1);
            wq[1] = cvtpk(p2, p3);
            *(uintx2*)(Pw + 128 * ln + ((32 * n + 8 * g) ^ swz)) = wq;
        }

        // ---- PV + l accumulation (P wave-private; same-wave DS in-order) ----
        #pragma unroll
        for (int kk = 0; kk < 2; ++kk) {
            bf16x8 vfv[4];
            #pragma unroll
            for (int n = 0; n < 4; ++n) {
                int row  = 16 * n + ln;                 // row&7 == ln&7
                int phys = 8 * sub + ((4 * kk + g) ^ (ln & 7));
                vfv[n] = *(const bf16x8*)&Vs[row * 256 + phys * 8];
            }
            bf16x8 pa = *(const bf16x8*)(Pw + 128 * ln + ((64 * kk + 16 * g) ^ swz));
            __builtin_amdgcn_s_setprio(1);
            #pragma unroll
            for (int n = 0; n < 4; ++n) O[n] = MFMA16(pa, vfv[n], O[n]);
            lacc = MFMA16(pa, onesf, lacc);
            __builtin_amdgcn_s_setprio(0);
        }
    };

    for (int tt = 0; tt < L_ / 256; ++tt) {
        stage(tt);
        __syncthreads();    // drains vmcnt(0): tile tt fully in LDS, all waves
        process(0);
        process(1);
        process(2);
        process(3);
        __syncthreads();    // all waves done reading before next stage
    }

    // epilogue: lacc[r] IS l for q=4g+r; normalize, write bf16 ao
    const int b = bh >> 4, hh = bh & 15;
    #pragma unroll
    for (int r = 0; r < 4; ++r) {
        float inv = 1.0f / lacc[r];
        int ql = q0 + 4 * g + r;
        ushort_t* dst = ao + ((size_t)(b * L_ + ql)) * D_ + hh * 64;
        #pragma unroll
        for (int n = 0; n < 4; ++n)
            dst[16 * n + ln] = f2bf(O[n][r] * inv);
    }
}

// ---------------------------------------------------------------------------
extern "C" void kernel_launch(void* const* d_in, const int* in_sizes, int n_in,
                              void* d_out, int out_size, void* d_ws, size_t ws_size,
                              hipStream_t stream)
{
    const float* x    = (const float*)d_in[0];
    const float* Wqkv = (const float*)d_in[1];
    const float* Wo   = (const float*)d_in[2];
    float* out = (float*)d_out;

    char* ws = (char*)d_ws;                               // 64 MB layout:
    ushort_t* xb  = (ushort_t*)(ws);                      // [0,8M)   x bf16; later ao
    ushort_t* wqt = (ushort_t*)(ws + ((size_t) 8 << 20)); // [8,14M)  Wqkv^T bf16
    ushort_t* wot = (ushort_t*)(ws + ((size_t)14 << 20)); // [14,16M) Wo^T bf16
    ushort_t* qR  = (ushort_t*)(ws + ((size_t)16 << 20)); // [16,24M) q rope'd (from GEMM)
    ushort_t* kR  = (ushort_t*)(ws + ((size_t)24 << 20)); // [24,32M) k rope'd (from GEMM)
    ushort_t* vt  = (ushort_t*)(ws + ((size_t)32 << 20)); // [32,40M) v^T (from GEMM)
    ushort_t* ao  = xb;                                   // alias (xb dead post-gemm)

    prep<<<3072, 256, 0, stream>>>(x, Wqkv, Wo, xb, wqt, wot);
    bgemm<1, 64, 128, N1_/128, 1536><<<1536, 256, 0, stream>>>(xb, wqt, nullptr, qR, kR, vt);
    attn_mfma<<<512, 512, 0, stream>>>(qR, kR, vt, ao);
    bgemm<0, 64, 64, D_/64, 1024><<<1024, 256, 0, stream>>>(ao, wot, out, nullptr, nullptr, nullptr);
}